// Round 1
// baseline (362.240 us; speedup 1.0000x reference)
//
#include <hip/hip_runtime.h>
#include <hip/hip_bf16.h>
#include <math.h>

#define B_ 8
#define T_ 1024
#define D_ 512
#define PRED 256
#define TP (T_ + PRED)
#define NH 8
#define DH 64
#define DFF 2048
#define CO 64
#define KSEL 8

typedef __hip_bfloat16 bf16;
using bf16x8 = __attribute__((ext_vector_type(8))) short;
using f32x4  = __attribute__((ext_vector_type(4))) float;

__device__ __forceinline__ void gload_lds16(const void* gp, void* lp) {
  __builtin_amdgcn_global_load_lds(
      (const __attribute__((address_space(1))) void*)gp,
      (__attribute__((address_space(3))) void*)lp, 16, 0, 0);
}

// ---------------- transpose res (b,T,D) -> resT (b,D,T) ----------------
__global__ __launch_bounds__(256) void k_transpose(const float* __restrict__ in, float* __restrict__ out) {
  __shared__ float tile[32][33];
  const int b = blockIdx.z;
  const int d0 = blockIdx.x * 32, t0 = blockIdx.y * 32;
  const int tx = threadIdx.x, ty = threadIdx.y;
  const float* src = in + ((size_t)b * T_ + t0) * D_ + d0;
#pragma unroll
  for (int i = 0; i < 32; i += 8) tile[ty + i][tx] = src[(size_t)(ty + i) * D_ + tx];
  __syncthreads();
  float* dst = out + ((size_t)b * D_ + d0) * T_ + t0;
#pragma unroll
  for (int i = 0; i < 32; i += 8) dst[(size_t)(ty + i) * T_ + tx] = tile[tx][ty + i];
}

// ---------------- 1024-pt real FFT per (b,d) + top-8 bins ----------------
// comp[bd][j] = {2*|X_k|/1024, (float)k, angle(X_k)} for the 8 largest |X_k|, k in 1..511
__global__ __launch_bounds__(256) void k_fft_topk(const float* __restrict__ xt, float* __restrict__ comp) {
  __shared__ float2 bA[512], bB[512], tw[256];
  __shared__ float xre[512], xim[512], mag2[512];
  __shared__ float wvv[4];
  __shared__ int wkk[4];
  __shared__ int selk[KSEL];
  const int j = threadIdx.x;
  const int bd = blockIdx.x;
  {
    float ang = -(6.283185307179586f / 512.0f) * (float)j;
    float sn, cs;
    sincosf(ang, &sn, &cs);
    tw[j] = make_float2(cs, sn);
  }
  const float4 v4 = ((const float4*)(xt + (size_t)bd * 1024))[j];
  bA[2 * j] = make_float2(v4.x, v4.y);
  bA[2 * j + 1] = make_float2(v4.z, v4.w);
  __syncthreads();
  // Stockham radix-2, 9 stages, 512-pt complex FFT (decim-in-freq, autosort)
#pragma unroll
  for (int st = 0; st < 9; ++st) {
    const int s = 1 << st;
    const int p = j >> st;
    const int q = j & (s - 1);
    const int m = 256 >> st;
    float2 a, b2;
    if ((st & 1) == 0) { a = bA[q + s * p]; b2 = bA[q + s * (p + m)]; }
    else               { a = bB[q + s * p]; b2 = bB[q + s * (p + m)]; }
    const float2 w = tw[p << st];
    float2 d0 = make_float2(a.x + b2.x, a.y + b2.y);
    const float ex = a.x - b2.x, ey = a.y - b2.y;
    float2 d1 = make_float2(ex * w.x - ey * w.y, ex * w.y + ey * w.x);
    if ((st & 1) == 0) { bB[q + s * 2 * p] = d0; bB[q + s * (2 * p + 1)] = d1; }
    else               { bA[q + s * 2 * p] = d0; bA[q + s * (2 * p + 1)] = d1; }
    __syncthreads();
  }
  // result Z in bB (natural order). Unpack to rfft X[k], k = 1..511
#pragma unroll
  for (int u = 0; u < 2; ++u) {
    const int k = (u == 0) ? (j + 1) : (j + 257);
    if (k <= 511) {
      const float2 zk = bB[k & 511];
      const float2 zm = bB[(512 - k) & 511];
      const float Ex = 0.5f * (zk.x + zm.x), Ey = 0.5f * (zk.y - zm.y);
      const float Ox = 0.5f * (zk.y + zm.y), Oy = 0.5f * (zm.x - zk.x);
      float sn, cs;
      sincosf(-(6.283185307179586f / 1024.0f) * (float)k, &sn, &cs);
      const float Xr = Ex + cs * Ox - sn * Oy;
      const float Xi = Ey + cs * Oy + sn * Ox;
      xre[k] = Xr; xim[k] = Xi; mag2[k] = Xr * Xr + Xi * Xi;
    }
  }
  if (j == 0) mag2[0] = -1.0f;
  __syncthreads();
  const int lane = j & 63, wvi = j >> 6;
  for (int r = 0; r < KSEL; ++r) {
    float bv = mag2[j];
    int bk = j;
    const float v2 = mag2[j + 256];
    if (v2 > bv) { bv = v2; bk = j + 256; }
#pragma unroll
    for (int off = 32; off; off >>= 1) {
      const float ov = __shfl_down(bv, off);
      const int ok = __shfl_down(bk, off);
      if (ov > bv || (ov == bv && ok < bk)) { bv = ov; bk = ok; }
    }
    if (lane == 0) { wvv[wvi] = bv; wkk[wvi] = bk; }
    __syncthreads();
    if (j == 0) {
      float fv = wvv[0];
      int fk = wkk[0];
#pragma unroll
      for (int i = 1; i < 4; i++)
        if (wvv[i] > fv || (wvv[i] == fv && wkk[i] < fk)) { fv = wvv[i]; fk = wkk[i]; }
      selk[r] = fk;
      mag2[fk] = -2.0f;
    }
    __syncthreads();
  }
  if (j < KSEL) {
    const int k = selk[j];
    const float re = xre[k], im = xim[k];
    float* o = comp + (size_t)bd * 24 + j * 3;
    o[0] = 2.0f * sqrtf(re * re + im * im) * (1.0f / 1024.0f);
    o[1] = (float)k;
    o[2] = atan2f(im, re);
  }
}

// ---------------- season synthesis + res1 = res - season ----------------
__global__ __launch_bounds__(512) void k_season(const float* __restrict__ comp, const float* __restrict__ res,
                                                float* __restrict__ season, bf16* __restrict__ res1b,
                                                bf16* __restrict__ seasb) {
  const int d = threadIdx.x;
  const int b = blockIdx.y;
  const int t0 = blockIdx.x * 5;
  float a_[8], kf_[8], ph_[8];
  const float* c = comp + ((size_t)b * 512 + d) * 24;
#pragma unroll
  for (int i = 0; i < 8; i++) { a_[i] = c[3 * i]; kf_[i] = c[3 * i + 1]; ph_[i] = c[3 * i + 2]; }
#pragma unroll
  for (int tt = 0; tt < 5; ++tt) {
    const int t = t0 + tt;
    float acc = 0.0f;
#pragma unroll
    for (int i = 0; i < 8; i++) {
      float fr = kf_[i] * (float)t * (1.0f / 1024.0f);  // k*t < 2^20: exact
      fr -= floorf(fr);
      acc += a_[i] * __cosf(fmaf(6.283185307179586f, fr, ph_[i]));
    }
    season[((size_t)b * TP + t) * D_ + d] = acc;
    if (t < T_) {
      const float rr = res[((size_t)b * T_ + t) * D_ + d] - acc;
      res1b[((size_t)b * T_ + t) * D_ + d] = __float2bfloat16(rr);
      seasb[((size_t)b * T_ + t) * D_ + d] = __float2bfloat16(acc);
    }
  }
}

// ---------------- f32 -> bf16 ----------------
__global__ void k_cvt(const float* __restrict__ in, bf16* __restrict__ out, int n) {
  const int i = blockIdx.x * 256 + threadIdx.x;
  if (i < n) out[i] = __float2bfloat16(in[i]);
}

// ---------------- growth exp-smooth scan: v -> s2 (bf16, 1025 rows/batch) ----------------
__global__ __launch_bounds__(64) void k_growth_scan(const float* __restrict__ v, const float* __restrict__ z0,
                                                    const float* __restrict__ sw, const float* __restrict__ v0,
                                                    bf16* __restrict__ s2) {
  const int b = blockIdx.x >> 3, h = blockIdx.x & 7, d = threadIdx.x;
  const int col = h * 64 + d;
  const float alpha = 1.0f / (1.0f + expf(-sw[h]));
  const float om = 1.0f - alpha;
  float vprev = z0[col];
  float s = v0[col];
  const float* vp = v + (size_t)b * T_ * D_ + col;
  bf16* op = s2 + (size_t)b * (T_ + 1) * D_ + col;
  op[0] = __float2bfloat16(s);
  for (int t0 = 0; t0 < T_; t0 += 16) {
    float nv[16];
#pragma unroll
    for (int i = 0; i < 16; i++) nv[i] = vp[(size_t)(t0 + i) * D_];
#pragma unroll
    for (int i = 0; i < 16; i++) {
      const float w = nv[i] - vprev;
      vprev = nv[i];
      s = alpha * s + om * w;
      op[(size_t)(t0 + i + 1) * D_] = __float2bfloat16(s);
    }
  }
}

// ---------------- level exp-smooth scan (with aux growth term) ----------------
__global__ __launch_bounds__(64) void k_level_scan(const float* __restrict__ level, const float* __restrict__ gp,
                                                   const float* __restrict__ sp, const float* __restrict__ sw,
                                                   const float* __restrict__ v0, float* __restrict__ out) {
  const int b = blockIdx.x, c = threadIdx.x;
  const float alpha = 1.0f / (1.0f + expf(-sw[c]));
  const float om = 1.0f - alpha;
  float s = v0[c];
  for (int t0 = 0; t0 < T_; t0 += 8) {
    float lv[8], spv[8], gpv[8];
#pragma unroll
    for (int i = 0; i < 8; i++) {
      const size_t idx = ((size_t)b * T_ + t0 + i) * CO + c;
      lv[i] = level[idx]; spv[i] = sp[idx]; gpv[i] = gp[idx];
    }
#pragma unroll
    for (int i = 0; i < 8; i++) {
      const float l = lv[i] - spv[i];
      s = alpha * s + om * l + alpha * gpv[i];
      out[((size_t)b * T_ + t0 + i) * CO + c] = s;
    }
  }
}

// ---------------- layer norm over D=512; MODE0: x = res - season - growth, +bf16 out ----------------
template <int MODE>
__global__ __launch_bounds__(128) void k_ln(const float* __restrict__ x1, const float* __restrict__ x2,
                                            const float* __restrict__ x3, const float* __restrict__ g,
                                            const float* __restrict__ be, float* __restrict__ outF,
                                            bf16* __restrict__ outB) {
  const int m = blockIdx.x, tid = threadIdx.x;
  const int b = m >> 10;
  float4 v = ((const float4*)(x1 + (size_t)m * D_))[tid];
  if (MODE == 0) {
    const float4 se = ((const float4*)(x2 + ((size_t)(m + b * PRED)) * D_))[tid];     // season row b*1280+t
    const float4 gr = ((const float4*)(x3 + ((size_t)(m + b + 1)) * D_))[tid];        // growth row b*1025+t+1
    v.x -= se.x + gr.x; v.y -= se.y + gr.y; v.z -= se.z + gr.z; v.w -= se.w + gr.w;
  }
  float s = v.x + v.y + v.z + v.w;
  float s2 = v.x * v.x + v.y * v.y + v.z * v.z + v.w * v.w;
#pragma unroll
  for (int off = 32; off; off >>= 1) { s += __shfl_down(s, off); s2 += __shfl_down(s2, off); }
  __shared__ float p1[2], p2[2];
  if ((tid & 63) == 0) { p1[tid >> 6] = s; p2[tid >> 6] = s2; }
  __syncthreads();
  const float S = p1[0] + p1[1], S2 = p2[0] + p2[1];
  const float mu = S * (1.0f / 512.0f);
  const float rs = rsqrtf(fmaxf(S2 * (1.0f / 512.0f) - mu * mu, 0.0f) + 1e-5f);
  const float4 gg = ((const float4*)g)[tid], bb = ((const float4*)be)[tid];
  float4 o;
  o.x = (v.x - mu) * rs * gg.x + bb.x;
  o.y = (v.y - mu) * rs * gg.y + bb.y;
  o.z = (v.z - mu) * rs * gg.z + bb.z;
  o.w = (v.w - mu) * rs * gg.w + bb.w;
  ((float4*)(outF + (size_t)m * D_))[tid] = o;
  if (MODE == 0) {
    bf16* ob = outB + (size_t)m * D_ + tid * 4;
    ob[0] = __float2bfloat16(o.x); ob[1] = __float2bfloat16(o.y);
    ob[2] = __float2bfloat16(o.z); ob[3] = __float2bfloat16(o.w);
  }
}

// ---------------- bf16 MFMA GEMM: C[m][n] = sum_k A[m][k]*B[n][k] (+bias, epilogue) ----------------
// EPI: 0 = bias+f32; 1 = bias+f32+bf16; 2 = sigmoid->bf16; 3 = f32 += resid (in place)
// extra: A physical row = m + (m>>10)*extra  (growth row mapping b*1025+t)
template <int BM, int BN, int EPI>
__global__ __launch_bounds__(256) void k_gemm(const bf16* __restrict__ A, const bf16* __restrict__ Bw,
                                              const float* __restrict__ bias, float* outF, bf16* __restrict__ outB,
                                              const float* resid, const int M, const int N, const int K,
                                              const int extra) {
  constexpr int BK = 32;
  constexpr int LA = BM / 64, LB = BN / 64;
  constexpr int WC = BN / 64 >= 2 ? 2 : 1;
  constexpr int WR = 4 / WC;
  static_assert(BM == WR * 64 && BN == WC * 64, "tile/wave mismatch");
  __shared__ bf16 lsA[2][BM * BK];
  __shared__ bf16 lsB[2][BN * BK];
  const int tid = threadIdx.x;
  const int w = tid >> 6, lane = tid & 63;
  const int tn = blockIdx.x, tm = blockIdx.y;
  const int wr = w / WC, wc = w % WC;
  const int r16 = lane & 15, hi = lane >> 4;
  const int srow = lane >> 2;  // staging row within 16-row group
  const int sch = lane & 3;    // staging 16B chunk within BK row

  const f32x4 fzero = {0.f, 0.f, 0.f, 0.f};
  f32x4 acc[4][4];
#pragma unroll
  for (int i = 0; i < 4; i++)
#pragma unroll
    for (int jj = 0; jj < 4; jj++) acc[i][jj] = fzero;

  const int NT = K / BK;

  auto stage = [&](int kt, int sel) {
#pragma unroll
    for (int q = 0; q < LA; q++) {
      const int g = w * LA + q;
      int m = tm * BM + g * 16 + srow;
      if (m > M - 1) m = M - 1;
      m += (m >> 10) * extra;
      gload_lds16(A + (size_t)m * K + (size_t)kt * BK + sch * 8, &lsA[sel][g * 512]);
    }
#pragma unroll
    for (int q = 0; q < LB; q++) {
      const int g = w * LB + q;
      const int n = tn * BN + g * 16 + srow;
      gload_lds16(Bw + (size_t)n * K + (size_t)kt * BK + sch * 8, &lsB[sel][g * 512]);
    }
  };

  stage(0, 0);
  __syncthreads();
  for (int kt = 0; kt < NT; ++kt) {
    const int sel = kt & 1;
    if (kt + 1 < NT) stage(kt + 1, sel ^ 1);
    bf16x8 af[4], bfv[4];
#pragma unroll
    for (int i = 0; i < 4; i++)
      af[i] = *(const bf16x8*)&lsA[sel][(wr * 64 + i * 16 + r16) * BK + hi * 8];
#pragma unroll
    for (int jj = 0; jj < 4; jj++)
      bfv[jj] = *(const bf16x8*)&lsB[sel][(wc * 64 + jj * 16 + r16) * BK + hi * 8];
#pragma unroll
    for (int i = 0; i < 4; i++)
#pragma unroll
      for (int jj = 0; jj < 4; jj++)
        acc[i][jj] = __builtin_amdgcn_mfma_f32_16x16x32_bf16(af[i], bfv[jj], acc[i][jj], 0, 0, 0);
    __syncthreads();
  }

#pragma unroll
  for (int i = 0; i < 4; i++) {
#pragma unroll
    for (int r = 0; r < 4; r++) {
      const int m = tm * BM + wr * 64 + i * 16 + hi * 4 + r;  // C/D: row=(lane>>4)*4+reg
      if (m < M) {
#pragma unroll
        for (int jj = 0; jj < 4; jj++) {
          const int n = tn * BN + wc * 64 + jj * 16 + r16;    // C/D: col=lane&15
          float x = acc[i][jj][r];
          if (bias) x += bias[n];
          const size_t idx = (size_t)m * N + n;
          if (EPI == 0) {
            outF[idx] = x;
          } else if (EPI == 1) {
            outF[idx] = x;
            outB[idx] = __float2bfloat16(x);
          } else if (EPI == 2) {
            outB[idx] = __float2bfloat16(1.0f / (1.0f + __expf(-x)));
          } else {
            outF[idx] = x + resid[idx];
          }
        }
      }
    }
  }
}

// ---------------- workspace layout ----------------
#define MB (size_t)(1u << 20)
static const size_t OFF_A = 0;          // 32MB: resT(f32,16MB) -> v(f32,16MB) -> h(bf16,32MB)
static const size_t OFF_C = 32 * MB;    // 8MB : res1 bf16 -> res2 bf16
static const size_t OFF_D = 40 * MB;    // 8MB : season bf16 (t<1024)
static const size_t OFF_E = 48 * MB;    // 6MB : weights bf16
static const size_t OFF_F = 54 * MB;    // 9MB : s2 bf16 (8200x512)
static const size_t OFF_G = 63 * MB;    // 9MB : growth bf16 (8200x512)
static const size_t OFF_H = 72 * MB;    // 16MB: res2 f32 (then pre-LN2 in place)
static const size_t OFF_J = 88 * MB;    // comp 4096x24 f32
static const size_t OFF_K = 89 * MB;    // g_proj f32 (8192x64)
static const size_t OFF_K2 = 91 * MB;   // s_proj f32 (8192x64)

// weight sub-offsets (elements) within OFF_E
#define W_IN 0
#define W_OUT 262144
#define W_FF1 524288
#define W_FF2 1572864
#define W_GW 2621440
#define W_SW2 2654208

extern "C" void kernel_launch(void* const* d_in, const int* in_sizes, int n_in, void* d_out, int out_size,
                              void* d_ws, size_t ws_size, hipStream_t stream) {
  (void)in_sizes; (void)n_in; (void)out_size; (void)ws_size;
  const float* res = (const float*)d_in[0];
  const float* level = (const float*)d_in[1];
  const float* gl_z0 = (const float*)d_in[2];
  const float* gl_in_w = (const float*)d_in[3];
  const float* gl_in_b = (const float*)d_in[4];
  const float* gl_sw = (const float*)d_in[5];
  const float* gl_v0 = (const float*)d_in[6];
  const float* gl_out_w = (const float*)d_in[7];
  const float* gl_out_b = (const float*)d_in[8];
  const float* ll_sw = (const float*)d_in[9];
  const float* ll_v0 = (const float*)d_in[10];
  const float* ll_gw = (const float*)d_in[11];
  const float* ll_gb = (const float*)d_in[12];
  const float* ll_sw2 = (const float*)d_in[13];
  const float* ll_sb = (const float*)d_in[14];
  const float* ff_w1 = (const float*)d_in[15];
  const float* ff_w2 = (const float*)d_in[16];
  const float* n1_g = (const float*)d_in[17];
  const float* n1_b = (const float*)d_in[18];
  const float* n2_g = (const float*)d_in[19];
  const float* n2_b = (const float*)d_in[20];

  char* ws = (char*)d_ws;
  float* resT = (float*)(ws + OFF_A);
  float* vbuf = (float*)(ws + OFF_A);
  bf16* hbuf = (bf16*)(ws + OFF_A);
  bf16* res1b = (bf16*)(ws + OFF_C);
  bf16* res2b = (bf16*)(ws + OFF_C);
  bf16* seasb = (bf16*)(ws + OFF_D);
  bf16* wE = (bf16*)(ws + OFF_E);
  bf16* s2b = (bf16*)(ws + OFF_F);
  bf16* grob = (bf16*)(ws + OFF_G);
  float* res2f = (float*)(ws + OFF_H);
  float* comp = (float*)(ws + OFF_J);
  float* gproj = (float*)(ws + OFF_K);
  float* sproj = (float*)(ws + OFF_K2);

  float* o_res = (float*)d_out;                  // (8,1024,512)
  float* o_level = o_res + 4194304;              // (8,1024,64)
  float* o_growth = o_level + 524288;            // (8,1025,512)
  float* o_season = o_growth + 4198400;          // (8,1280,512)

  // 1) transpose for FFT
  k_transpose<<<dim3(16, 32, 8), dim3(32, 8), 0, stream>>>(res, resT);
  // 2) FFT + top-8
  k_fft_topk<<<4096, 256, 0, stream>>>(resT, comp);
  // 3) season synthesis (+ res1 bf16, season bf16)
  k_season<<<dim3(256, 8), 512, 0, stream>>>(comp, res, o_season, res1b, seasb);
  // 4) weight conversions
  k_cvt<<<(262144 + 255) / 256, 256, 0, stream>>>(gl_in_w, wE + W_IN, 262144);
  k_cvt<<<(262144 + 255) / 256, 256, 0, stream>>>(gl_out_w, wE + W_OUT, 262144);
  k_cvt<<<(1048576 + 255) / 256, 256, 0, stream>>>(ff_w1, wE + W_FF1, 1048576);
  k_cvt<<<(1048576 + 255) / 256, 256, 0, stream>>>(ff_w2, wE + W_FF2, 1048576);
  k_cvt<<<(32768 + 255) / 256, 256, 0, stream>>>(ll_gw, wE + W_GW, 32768);
  k_cvt<<<(32768 + 255) / 256, 256, 0, stream>>>(ll_sw2, wE + W_SW2, 32768);
  // 5) v = res1 @ gl_in_w^T + b
  k_gemm<128, 128, 0><<<dim3(4, 64), 256, 0, stream>>>(res1b, wE + W_IN, gl_in_b, vbuf, nullptr, nullptr, 8192, 512, 512, 0);
  // 6) growth scan -> s2 (bf16)
  k_growth_scan<<<64, 64, 0, stream>>>(vbuf, gl_z0, gl_sw, gl_v0, s2b);
  // 7) growth = s2 @ gl_out_w^T + b  (f32 to d_out + bf16 copy)
  k_gemm<128, 128, 1><<<dim3(4, 65), 256, 0, stream>>>(s2b, wE + W_OUT, gl_out_b, o_growth, grob, nullptr, 8200, 512, 512, 0);
  // 8) res2 = LN1(res - season - growth[:,1:])
  k_ln<0><<<8192, 128, 0, stream>>>(res, o_season, o_growth, n1_g, n1_b, res2f, res2b);
  // 9) h = sigmoid(res2 @ ff_w1^T)  (bf16)
  k_gemm<128, 128, 2><<<dim3(16, 64), 256, 0, stream>>>(res2b, wE + W_FF1, nullptr, nullptr, hbuf, nullptr, 8192, 2048, 512, 0);
  // 10) pre = res2 + h @ ff_w2^T  (in place into res2f)
  k_gemm<128, 128, 3><<<dim3(4, 64), 256, 0, stream>>>(hbuf, wE + W_FF2, nullptr, res2f, nullptr, res2f, 8192, 512, 2048, 0);
  // 11) res = LN2(pre)
  k_ln<1><<<8192, 128, 0, stream>>>(res2f, nullptr, nullptr, n2_g, n2_b, o_res, nullptr);
  // 12) g_proj = growth[:, :-1] @ ll_gw^T + b   (row map m -> m + m>>10)
  k_gemm<256, 64, 0><<<dim3(1, 32), 256, 0, stream>>>(grob, wE + W_GW, ll_gb, gproj, nullptr, nullptr, 8192, 64, 512, 1);
  // 13) s_proj = season[:, :1024] @ ll_sw2^T + b
  k_gemm<256, 64, 0><<<dim3(1, 32), 256, 0, stream>>>(seasb, wE + W_SW2, ll_sb, sproj, nullptr, nullptr, 8192, 64, 512, 0);
  // 14) level scan
  k_level_scan<<<8, 64, 0, stream>>>(level, gproj, sproj, ll_sw, ll_v0, o_level);
}

// Round 2
// 292.750 us; speedup vs baseline: 1.2374x; 1.2374x over previous
//
#include <hip/hip_runtime.h>
#include <hip/hip_bf16.h>
#include <math.h>

#define B_ 8
#define T_ 1024
#define D_ 512
#define PRED 256
#define TP (T_ + PRED)
#define NH 8
#define DH 64
#define DFF 2048
#define CO 64
#define KSEL 8

typedef __hip_bfloat16 bf16;
using bf16x8 = __attribute__((ext_vector_type(8))) short;
using f32x4  = __attribute__((ext_vector_type(4))) float;

__device__ __forceinline__ void gload_lds16(const void* gp, void* lp) {
  __builtin_amdgcn_global_load_lds(
      (const __attribute__((address_space(1))) void*)gp,
      (__attribute__((address_space(3))) void*)lp, 16, 0, 0);
}

// ---------------- transpose res (b,T,D) -> resT (b,D,T) ----------------
__global__ __launch_bounds__(256) void k_transpose(const float* __restrict__ in, float* __restrict__ out) {
  __shared__ float tile[32][33];
  const int b = blockIdx.z;
  const int d0 = blockIdx.x * 32, t0 = blockIdx.y * 32;
  const int tx = threadIdx.x, ty = threadIdx.y;
  const float* src = in + ((size_t)b * T_ + t0) * D_ + d0;
#pragma unroll
  for (int i = 0; i < 32; i += 8) tile[ty + i][tx] = src[(size_t)(ty + i) * D_ + tx];
  __syncthreads();
  float* dst = out + ((size_t)b * D_ + d0) * T_ + t0;
#pragma unroll
  for (int i = 0; i < 32; i += 8) dst[(size_t)(ty + i) * T_ + tx] = tile[tx][ty + i];
}

// ---------------- 1024-pt real FFT per (b,d) + top-8 bins ----------------
__global__ __launch_bounds__(256) void k_fft_topk(const float* __restrict__ xt, float* __restrict__ comp) {
  __shared__ float2 bA[512], bB[512], tw[256];
  __shared__ float xre[512], xim[512], mag2[512];
  __shared__ float wvv[4];
  __shared__ int wkk[4];
  __shared__ int selk[KSEL];
  const int j = threadIdx.x;
  const int bd = blockIdx.x;
  {
    float ang = -(6.283185307179586f / 512.0f) * (float)j;
    float sn, cs;
    sincosf(ang, &sn, &cs);
    tw[j] = make_float2(cs, sn);
  }
  const float4 v4 = ((const float4*)(xt + (size_t)bd * 1024))[j];
  bA[2 * j] = make_float2(v4.x, v4.y);
  bA[2 * j + 1] = make_float2(v4.z, v4.w);
  __syncthreads();
#pragma unroll
  for (int st = 0; st < 9; ++st) {
    const int s = 1 << st;
    const int p = j >> st;
    const int q = j & (s - 1);
    const int m = 256 >> st;
    float2 a, b2;
    if ((st & 1) == 0) { a = bA[q + s * p]; b2 = bA[q + s * (p + m)]; }
    else               { a = bB[q + s * p]; b2 = bB[q + s * (p + m)]; }
    const float2 w = tw[p << st];
    float2 d0 = make_float2(a.x + b2.x, a.y + b2.y);
    const float ex = a.x - b2.x, ey = a.y - b2.y;
    float2 d1 = make_float2(ex * w.x - ey * w.y, ex * w.y + ey * w.x);
    if ((st & 1) == 0) { bB[q + s * 2 * p] = d0; bB[q + s * (2 * p + 1)] = d1; }
    else               { bA[q + s * 2 * p] = d0; bA[q + s * (2 * p + 1)] = d1; }
    __syncthreads();
  }
#pragma unroll
  for (int u = 0; u < 2; ++u) {
    const int k = (u == 0) ? (j + 1) : (j + 257);
    if (k <= 511) {
      const float2 zk = bB[k & 511];
      const float2 zm = bB[(512 - k) & 511];
      const float Ex = 0.5f * (zk.x + zm.x), Ey = 0.5f * (zk.y - zm.y);
      const float Ox = 0.5f * (zk.y + zm.y), Oy = 0.5f * (zm.x - zk.x);
      float sn, cs;
      sincosf(-(6.283185307179586f / 1024.0f) * (float)k, &sn, &cs);
      const float Xr = Ex + cs * Ox - sn * Oy;
      const float Xi = Ey + cs * Oy + sn * Ox;
      xre[k] = Xr; xim[k] = Xi; mag2[k] = Xr * Xr + Xi * Xi;
    }
  }
  if (j == 0) mag2[0] = -1.0f;
  __syncthreads();
  const int lane = j & 63, wvi = j >> 6;
  for (int r = 0; r < KSEL; ++r) {
    float bv = mag2[j];
    int bk = j;
    const float v2 = mag2[j + 256];
    if (v2 > bv) { bv = v2; bk = j + 256; }
#pragma unroll
    for (int off = 32; off; off >>= 1) {
      const float ov = __shfl_down(bv, off);
      const int ok = __shfl_down(bk, off);
      if (ov > bv || (ov == bv && ok < bk)) { bv = ov; bk = ok; }
    }
    if (lane == 0) { wvv[wvi] = bv; wkk[wvi] = bk; }
    __syncthreads();
    if (j == 0) {
      float fv = wvv[0];
      int fk = wkk[0];
#pragma unroll
      for (int i = 1; i < 4; i++)
        if (wvv[i] > fv || (wvv[i] == fv && wkk[i] < fk)) { fv = wvv[i]; fk = wkk[i]; }
      selk[r] = fk;
      mag2[fk] = -2.0f;
    }
    __syncthreads();
  }
  if (j < KSEL) {
    const int k = selk[j];
    const float re = xre[k], im = xim[k];
    float* o = comp + (size_t)bd * 24 + j * 3;
    o[0] = 2.0f * sqrtf(re * re + im * im) * (1.0f / 1024.0f);
    o[1] = (float)k;
    o[2] = atan2f(im, re);
  }
}

// ---------------- season synthesis + res1 = res - season ----------------
__global__ __launch_bounds__(512) void k_season(const float* __restrict__ comp, const float* __restrict__ res,
                                                float* __restrict__ season, bf16* __restrict__ res1b,
                                                bf16* __restrict__ seasb) {
  const int d = threadIdx.x;
  const int b = blockIdx.y;
  const int t0 = blockIdx.x * 5;
  float a_[8], kf_[8], ph_[8];
  const float* c = comp + ((size_t)b * 512 + d) * 24;
#pragma unroll
  for (int i = 0; i < 8; i++) { a_[i] = c[3 * i]; kf_[i] = c[3 * i + 1]; ph_[i] = c[3 * i + 2]; }
#pragma unroll
  for (int tt = 0; tt < 5; ++tt) {
    const int t = t0 + tt;
    float acc = 0.0f;
#pragma unroll
    for (int i = 0; i < 8; i++) {
      float fr = kf_[i] * (float)t * (1.0f / 1024.0f);
      fr -= floorf(fr);
      acc += a_[i] * __cosf(fmaf(6.283185307179586f, fr, ph_[i]));
    }
    season[((size_t)b * TP + t) * D_ + d] = acc;
    if (t < T_) {
      const float rr = res[((size_t)b * T_ + t) * D_ + d] - acc;
      res1b[((size_t)b * T_ + t) * D_ + d] = __float2bfloat16(rr);
      seasb[((size_t)b * T_ + t) * D_ + d] = __float2bfloat16(acc);
    }
  }
}

// ---------------- fused f32 -> bf16 for all 6 weight tensors ----------------
#define CVT_TOTAL 2686976
__global__ __launch_bounds__(256) void k_cvt_all(const float* __restrict__ s0, const float* __restrict__ s1,
                                                 const float* __restrict__ s2_, const float* __restrict__ s3,
                                                 const float* __restrict__ s4, const float* __restrict__ s5,
                                                 bf16* __restrict__ dst) {
  const int i = (blockIdx.x * 256 + threadIdx.x) * 4;
  if (i >= CVT_TOTAL) return;
  const float* src;
  int off;
  if (i < 262144)       { src = s0;  off = i; }
  else if (i < 524288)  { src = s1;  off = i - 262144; }
  else if (i < 1572864) { src = s2_; off = i - 524288; }
  else if (i < 2621440) { src = s3;  off = i - 1572864; }
  else if (i < 2654208) { src = s4;  off = i - 2621440; }
  else                  { src = s5;  off = i - 2654208; }
  const float4 v = *(const float4*)(src + off);
  bf16* o = dst + i;
  o[0] = __float2bfloat16(v.x); o[1] = __float2bfloat16(v.y);
  o[2] = __float2bfloat16(v.z); o[3] = __float2bfloat16(v.w);
}

// ---------------- growth exp-smooth blocked scan (serial depth 1024 -> 128) ----------------
// s[t] = a*s[t-1] + (1-a)*(v[t]-v[t-1]), s[-1]=v0, v[-1]=z0; out s2[0]=v0, s2[t+1]=s[t]
__global__ __launch_bounds__(1024) void k_growth_scan2(const float* __restrict__ v, const float* __restrict__ z0,
                                                       const float* __restrict__ sw, const float* __restrict__ v0,
                                                       bf16* __restrict__ s2) {
  const int b = blockIdx.x >> 3;
  const int col = (blockIdx.x & 7) * 64 + (threadIdx.x & 63);
  const int w = threadIdx.x >> 6;  // t-segment 0..15 (64 steps each)
  const float alpha = 1.0f / (1.0f + expf(-sw[col >> 6]));
  const float om = 1.0f - alpha;
  float a64 = alpha;
#pragma unroll
  for (int i = 0; i < 6; i++) a64 *= a64;
  const float* vp = v + (size_t)b * T_ * D_ + col;
  // phase 1: zero-init local scan tail
  float vprev = (w == 0) ? z0[col] : vp[(size_t)(64 * w - 1) * D_];
  float sloc = 0.0f;
#pragma unroll 8
  for (int j = 0; j < 64; j++) {
    const float nv = vp[(size_t)(64 * w + j) * D_];
    sloc = alpha * sloc + om * (nv - vprev);
    vprev = nv;
  }
  __shared__ float lb[16][64], lc[16][64];
  lb[w][threadIdx.x & 63] = sloc;
  __syncthreads();
  // phase 2: carry scan across 16 segments (multiplier a^64)
  if (w == 0) {
    float s = v0[col];
#pragma unroll
    for (int k = 0; k < 16; k++) { lc[k][threadIdx.x & 63] = s; s = a64 * s + lb[k][threadIdx.x & 63]; }
  }
  __syncthreads();
  // phase 3: replay with carry-in
  float s = lc[w][threadIdx.x & 63];
  vprev = (w == 0) ? z0[col] : vp[(size_t)(64 * w - 1) * D_];
  bf16* op = s2 + (size_t)b * (T_ + 1) * D_ + col;
  if (w == 0) op[0] = __float2bfloat16(v0[col]);
#pragma unroll 8
  for (int j = 0; j < 64; j++) {
    const float nv = vp[(size_t)(64 * w + j) * D_];
    s = alpha * s + om * (nv - vprev);
    vprev = nv;
    op[(size_t)(64 * w + j + 1) * D_] = __float2bfloat16(s);
  }
}

// ---------------- level exp-smooth blocked scan ----------------
// s[t] = a*s[t-1] + (1-a)*(level[t]-sp[t]) + a*gp[t], s[-1]=v0
__global__ __launch_bounds__(1024) void k_level_scan2(const float* __restrict__ level, const float* __restrict__ gp,
                                                      const float* __restrict__ sp, const float* __restrict__ sw,
                                                      const float* __restrict__ v0, float* __restrict__ out) {
  const int b = blockIdx.x;
  const int w = threadIdx.x >> 6;
  const int c = threadIdx.x & 63;
  const float alpha = 1.0f / (1.0f + expf(-sw[c]));
  const float om = 1.0f - alpha;
  float a64 = alpha;
#pragma unroll
  for (int i = 0; i < 6; i++) a64 *= a64;
  const size_t base = ((size_t)b * T_ + 64 * w) * CO + c;
  // phase 1: compute u, stash in out, local zero-init scan tail
  float sloc = 0.0f;
#pragma unroll 8
  for (int j = 0; j < 64; j++) {
    const size_t idx = base + (size_t)j * CO;
    const float u = om * (level[idx] - sp[idx]) + alpha * gp[idx];
    out[idx] = u;
    sloc = alpha * sloc + u;
  }
  __shared__ float lb[16][64], lc[16][64];
  lb[w][c] = sloc;
  __syncthreads();
  if (w == 0) {
    float s = v0[c];
#pragma unroll
    for (int k = 0; k < 16; k++) { lc[k][c] = s; s = a64 * s + lb[k][c]; }
  }
  __syncthreads();
  // phase 3: replay from own stashed u (same-thread RAW, cache-resident)
  float s = lc[w][c];
#pragma unroll 8
  for (int j = 0; j < 64; j++) {
    const size_t idx = base + (size_t)j * CO;
    s = alpha * s + out[idx];
    out[idx] = s;
  }
}

// ---------------- layer norm over D=512 ----------------
template <int MODE>
__global__ __launch_bounds__(128) void k_ln(const float* __restrict__ x1, const float* __restrict__ x2,
                                            const float* __restrict__ x3, const float* __restrict__ g,
                                            const float* __restrict__ be, float* __restrict__ outF,
                                            bf16* __restrict__ outB) {
  const int m = blockIdx.x, tid = threadIdx.x;
  const int b = m >> 10;
  float4 v = ((const float4*)(x1 + (size_t)m * D_))[tid];
  if (MODE == 0) {
    const float4 se = ((const float4*)(x2 + ((size_t)(m + b * PRED)) * D_))[tid];
    const float4 gr = ((const float4*)(x3 + ((size_t)(m + b + 1)) * D_))[tid];
    v.x -= se.x + gr.x; v.y -= se.y + gr.y; v.z -= se.z + gr.z; v.w -= se.w + gr.w;
  }
  float s = v.x + v.y + v.z + v.w;
  float s2 = v.x * v.x + v.y * v.y + v.z * v.z + v.w * v.w;
#pragma unroll
  for (int off = 32; off; off >>= 1) { s += __shfl_down(s, off); s2 += __shfl_down(s2, off); }
  __shared__ float p1[2], p2[2];
  if ((tid & 63) == 0) { p1[tid >> 6] = s; p2[tid >> 6] = s2; }
  __syncthreads();
  const float S = p1[0] + p1[1], S2 = p2[0] + p2[1];
  const float mu = S * (1.0f / 512.0f);
  const float rs = rsqrtf(fmaxf(S2 * (1.0f / 512.0f) - mu * mu, 0.0f) + 1e-5f);
  const float4 gg = ((const float4*)g)[tid], bb = ((const float4*)be)[tid];
  float4 o;
  o.x = (v.x - mu) * rs * gg.x + bb.x;
  o.y = (v.y - mu) * rs * gg.y + bb.y;
  o.z = (v.z - mu) * rs * gg.z + bb.z;
  o.w = (v.w - mu) * rs * gg.w + bb.w;
  ((float4*)(outF + (size_t)m * D_))[tid] = o;
  if (MODE == 0) {
    bf16* ob = outB + (size_t)m * D_ + tid * 4;
    ob[0] = __float2bfloat16(o.x); ob[1] = __float2bfloat16(o.y);
    ob[2] = __float2bfloat16(o.z); ob[3] = __float2bfloat16(o.w);
  }
}

// ---------------- bf16 MFMA GEMM ----------------
template <int BM, int BN, int EPI>
__global__ __launch_bounds__(256) void k_gemm(const bf16* __restrict__ A, const bf16* __restrict__ Bw,
                                              const float* __restrict__ bias, float* outF, bf16* __restrict__ outB,
                                              const float* resid, const int M, const int N, const int K,
                                              const int extra) {
  constexpr int BK = 32;
  constexpr int LA = BM / 64, LB = BN / 64;
  constexpr int WC = BN / 64 >= 2 ? 2 : 1;
  constexpr int WR = 4 / WC;
  static_assert(BM == WR * 64 && BN == WC * 64, "tile/wave mismatch");
  __shared__ bf16 lsA[2][BM * BK];
  __shared__ bf16 lsB[2][BN * BK];
  const int tid = threadIdx.x;
  const int w = tid >> 6, lane = tid & 63;
  const int tn = blockIdx.x, tm = blockIdx.y;
  const int wr = w / WC, wc = w % WC;
  const int r16 = lane & 15, hi = lane >> 4;
  const int srow = lane >> 2;
  const int sch = lane & 3;

  const f32x4 fzero = {0.f, 0.f, 0.f, 0.f};
  f32x4 acc[4][4];
#pragma unroll
  for (int i = 0; i < 4; i++)
#pragma unroll
    for (int jj = 0; jj < 4; jj++) acc[i][jj] = fzero;

  const int NT = K / BK;

  auto stage = [&](int kt, int sel) {
#pragma unroll
    for (int q = 0; q < LA; q++) {
      const int g = w * LA + q;
      int m = tm * BM + g * 16 + srow;
      if (m > M - 1) m = M - 1;
      m += (m >> 10) * extra;
      gload_lds16(A + (size_t)m * K + (size_t)kt * BK + sch * 8, &lsA[sel][g * 512]);
    }
#pragma unroll
    for (int q = 0; q < LB; q++) {
      const int g = w * LB + q;
      const int n = tn * BN + g * 16 + srow;
      gload_lds16(Bw + (size_t)n * K + (size_t)kt * BK + sch * 8, &lsB[sel][g * 512]);
    }
  };

  stage(0, 0);
  __syncthreads();
  for (int kt = 0; kt < NT; ++kt) {
    const int sel = kt & 1;
    if (kt + 1 < NT) stage(kt + 1, sel ^ 1);
    bf16x8 af[4], bfv[4];
#pragma unroll
    for (int i = 0; i < 4; i++)
      af[i] = *(const bf16x8*)&lsA[sel][(wr * 64 + i * 16 + r16) * BK + hi * 8];
#pragma unroll
    for (int jj = 0; jj < 4; jj++)
      bfv[jj] = *(const bf16x8*)&lsB[sel][(wc * 64 + jj * 16 + r16) * BK + hi * 8];
#pragma unroll
    for (int i = 0; i < 4; i++)
#pragma unroll
      for (int jj = 0; jj < 4; jj++)
        acc[i][jj] = __builtin_amdgcn_mfma_f32_16x16x32_bf16(af[i], bfv[jj], acc[i][jj], 0, 0, 0);
    __syncthreads();
  }

#pragma unroll
  for (int i = 0; i < 4; i++) {
#pragma unroll
    for (int r = 0; r < 4; r++) {
      const int m = tm * BM + wr * 64 + i * 16 + hi * 4 + r;
      if (m < M) {
#pragma unroll
        for (int jj = 0; jj < 4; jj++) {
          const int n = tn * BN + wc * 64 + jj * 16 + r16;
          float x = acc[i][jj][r];
          if (bias) x += bias[n];
          const size_t idx = (size_t)m * N + n;
          if (EPI == 0) {
            outF[idx] = x;
          } else if (EPI == 1) {
            outF[idx] = x;
            outB[idx] = __float2bfloat16(x);
          } else if (EPI == 2) {
            outB[idx] = __float2bfloat16(1.0f / (1.0f + __expf(-x)));
          } else {
            outF[idx] = x + resid[idx];
          }
        }
      }
    }
  }
}

// ---------------- workspace layout ----------------
#define MB (size_t)(1u << 20)
static const size_t OFF_A = 0;
static const size_t OFF_C = 32 * MB;
static const size_t OFF_D = 40 * MB;
static const size_t OFF_E = 48 * MB;
static const size_t OFF_F = 54 * MB;
static const size_t OFF_G = 63 * MB;
static const size_t OFF_H = 72 * MB;
static const size_t OFF_J = 88 * MB;
static const size_t OFF_K = 89 * MB;
static const size_t OFF_K2 = 91 * MB;

#define W_IN 0
#define W_OUT 262144
#define W_FF1 524288
#define W_FF2 1572864
#define W_GW 2621440
#define W_SW2 2654208

extern "C" void kernel_launch(void* const* d_in, const int* in_sizes, int n_in, void* d_out, int out_size,
                              void* d_ws, size_t ws_size, hipStream_t stream) {
  (void)in_sizes; (void)n_in; (void)out_size; (void)ws_size;
  const float* res = (const float*)d_in[0];
  const float* level = (const float*)d_in[1];
  const float* gl_z0 = (const float*)d_in[2];
  const float* gl_in_w = (const float*)d_in[3];
  const float* gl_in_b = (const float*)d_in[4];
  const float* gl_sw = (const float*)d_in[5];
  const float* gl_v0 = (const float*)d_in[6];
  const float* gl_out_w = (const float*)d_in[7];
  const float* gl_out_b = (const float*)d_in[8];
  const float* ll_sw = (const float*)d_in[9];
  const float* ll_v0 = (const float*)d_in[10];
  const float* ll_gw = (const float*)d_in[11];
  const float* ll_gb = (const float*)d_in[12];
  const float* ll_sw2 = (const float*)d_in[13];
  const float* ll_sb = (const float*)d_in[14];
  const float* ff_w1 = (const float*)d_in[15];
  const float* ff_w2 = (const float*)d_in[16];
  const float* n1_g = (const float*)d_in[17];
  const float* n1_b = (const float*)d_in[18];
  const float* n2_g = (const float*)d_in[19];
  const float* n2_b = (const float*)d_in[20];

  char* ws = (char*)d_ws;
  float* resT = (float*)(ws + OFF_A);
  float* vbuf = (float*)(ws + OFF_A);
  bf16* hbuf = (bf16*)(ws + OFF_A);
  bf16* res1b = (bf16*)(ws + OFF_C);
  bf16* res2b = (bf16*)(ws + OFF_C);
  bf16* seasb = (bf16*)(ws + OFF_D);
  bf16* wE = (bf16*)(ws + OFF_E);
  bf16* s2b = (bf16*)(ws + OFF_F);
  bf16* grob = (bf16*)(ws + OFF_G);
  float* res2f = (float*)(ws + OFF_H);
  float* comp = (float*)(ws + OFF_J);
  float* gproj = (float*)(ws + OFF_K);
  float* sproj = (float*)(ws + OFF_K2);

  float* o_res = (float*)d_out;
  float* o_level = o_res + 4194304;
  float* o_growth = o_level + 524288;
  float* o_season = o_growth + 4198400;

  k_transpose<<<dim3(16, 32, 8), dim3(32, 8), 0, stream>>>(res, resT);
  k_fft_topk<<<4096, 256, 0, stream>>>(resT, comp);
  k_season<<<dim3(256, 8), 512, 0, stream>>>(comp, res, o_season, res1b, seasb);
  k_cvt_all<<<(CVT_TOTAL / 4 + 255) / 256, 256, 0, stream>>>(gl_in_w, gl_out_w, ff_w1, ff_w2, ll_gw, ll_sw2, wE);
  k_gemm<128, 128, 0><<<dim3(4, 64), 256, 0, stream>>>(res1b, wE + W_IN, gl_in_b, vbuf, nullptr, nullptr, 8192, 512, 512, 0);
  k_growth_scan2<<<64, 1024, 0, stream>>>(vbuf, gl_z0, gl_sw, gl_v0, s2b);
  k_gemm<128, 128, 1><<<dim3(4, 65), 256, 0, stream>>>(s2b, wE + W_OUT, gl_out_b, o_growth, grob, nullptr, 8200, 512, 512, 0);
  k_ln<0><<<8192, 128, 0, stream>>>(res, o_season, o_growth, n1_g, n1_b, res2f, res2b);
  k_gemm<128, 128, 2><<<dim3(16, 64), 256, 0, stream>>>(res2b, wE + W_FF1, nullptr, nullptr, hbuf, nullptr, 8192, 2048, 512, 0);
  k_gemm<128, 128, 3><<<dim3(4, 64), 256, 0, stream>>>(hbuf, wE + W_FF2, nullptr, res2f, nullptr, res2f, 8192, 512, 2048, 0);
  k_ln<1><<<8192, 128, 0, stream>>>(res2f, nullptr, nullptr, n2_g, n2_b, o_res, nullptr);
  k_gemm<256, 64, 0><<<dim3(1, 32), 256, 0, stream>>>(grob, wE + W_GW, ll_gb, gproj, nullptr, nullptr, 8192, 64, 512, 1);
  k_gemm<256, 64, 0><<<dim3(1, 32), 256, 0, stream>>>(seasb, wE + W_SW2, ll_sb, sproj, nullptr, nullptr, 8192, 64, 512, 0);
  k_level_scan2<<<8, 1024, 0, stream>>>(level, gproj, sproj, ll_sw, ll_v0, o_level);
}

// Round 7
// 272.750 us; speedup vs baseline: 1.3281x; 1.0733x over previous
//
#include <hip/hip_runtime.h>
#include <hip/hip_bf16.h>
#include <math.h>

#define B_ 8
#define T_ 1024
#define D_ 512
#define PRED 256
#define TP (T_ + PRED)
#define NH 8
#define DH 64
#define DFF 2048
#define CO 64
#define KSEL 8

typedef __hip_bfloat16 bf16;
using bf16x8 = __attribute__((ext_vector_type(8))) short;
using f32x4  = __attribute__((ext_vector_type(4))) float;

__device__ __forceinline__ void gload_lds16(const void* gp, void* lp) {
  __builtin_amdgcn_global_load_lds(
      (const __attribute__((address_space(1))) void*)gp,
      (__attribute__((address_space(3))) void*)lp, 16, 0, 0);
}

// ---------------- transpose res (b,T,D) -> resT (b,D,T) ----------------
__global__ __launch_bounds__(256) void k_transpose(const float* __restrict__ in, float* __restrict__ out) {
  __shared__ float tile[32][33];
  const int b = blockIdx.z;
  const int d0 = blockIdx.x * 32, t0 = blockIdx.y * 32;
  const int tx = threadIdx.x, ty = threadIdx.y;
  const float* src = in + ((size_t)b * T_ + t0) * D_ + d0;
#pragma unroll
  for (int i = 0; i < 32; i += 8) tile[ty + i][tx] = src[(size_t)(ty + i) * D_ + tx];
  __syncthreads();
  float* dst = out + ((size_t)b * D_ + d0) * T_ + t0;
#pragma unroll
  for (int i = 0; i < 32; i += 8) dst[(size_t)(ty + i) * T_ + tx] = tile[tx][ty + i];
}

// ---------------- 1024-pt real FFT per (b,d) + top-8 bins ----------------
__global__ __launch_bounds__(256) void k_fft_topk(const float* __restrict__ xt, float* __restrict__ comp) {
  __shared__ float2 bA[512], bB[512], tw[256];
  __shared__ float xre[512], xim[512], mag2[512];
  __shared__ float wvv[4];
  __shared__ int wkk[4];
  __shared__ int selk[KSEL];
  const int j = threadIdx.x;
  const int bd = blockIdx.x;
  {
    float ang = -(6.283185307179586f / 512.0f) * (float)j;
    float sn, cs;
    sincosf(ang, &sn, &cs);
    tw[j] = make_float2(cs, sn);
  }
  const float4 v4 = ((const float4*)(xt + (size_t)bd * 1024))[j];
  bA[2 * j] = make_float2(v4.x, v4.y);
  bA[2 * j + 1] = make_float2(v4.z, v4.w);
  __syncthreads();
#pragma unroll
  for (int st = 0; st < 9; ++st) {
    const int s = 1 << st;
    const int p = j >> st;
    const int q = j & (s - 1);
    const int m = 256 >> st;
    float2 a, b2;
    if ((st & 1) == 0) { a = bA[q + s * p]; b2 = bA[q + s * (p + m)]; }
    else               { a = bB[q + s * p]; b2 = bB[q + s * (p + m)]; }
    const float2 w = tw[p << st];
    float2 d0 = make_float2(a.x + b2.x, a.y + b2.y);
    const float ex = a.x - b2.x, ey = a.y - b2.y;
    float2 d1 = make_float2(ex * w.x - ey * w.y, ex * w.y + ey * w.x);
    if ((st & 1) == 0) { bB[q + s * 2 * p] = d0; bB[q + s * (2 * p + 1)] = d1; }
    else               { bA[q + s * 2 * p] = d0; bA[q + s * (2 * p + 1)] = d1; }
    __syncthreads();
  }
#pragma unroll
  for (int u = 0; u < 2; ++u) {
    const int k = (u == 0) ? (j + 1) : (j + 257);
    if (k <= 511) {
      const float2 zk = bB[k & 511];
      const float2 zm = bB[(512 - k) & 511];
      const float Ex = 0.5f * (zk.x + zm.x), Ey = 0.5f * (zk.y - zm.y);
      const float Ox = 0.5f * (zk.y + zm.y), Oy = 0.5f * (zm.x - zk.x);
      float sn, cs;
      sincosf(-(6.283185307179586f / 1024.0f) * (float)k, &sn, &cs);
      const float Xr = Ex + cs * Ox - sn * Oy;
      const float Xi = Ey + cs * Oy + sn * Ox;
      xre[k] = Xr; xim[k] = Xi; mag2[k] = Xr * Xr + Xi * Xi;
    }
  }
  if (j == 0) mag2[0] = -1.0f;
  __syncthreads();
  const int lane = j & 63, wvi = j >> 6;
  for (int r = 0; r < KSEL; ++r) {
    float bv = mag2[j];
    int bk = j;
    const float v2 = mag2[j + 256];
    if (v2 > bv) { bv = v2; bk = j + 256; }
#pragma unroll
    for (int off = 32; off; off >>= 1) {
      const float ov = __shfl_down(bv, off);
      const int ok = __shfl_down(bk, off);
      if (ov > bv || (ov == bv && ok < bk)) { bv = ov; bk = ok; }
    }
    if (lane == 0) { wvv[wvi] = bv; wkk[wvi] = bk; }
    __syncthreads();
    if (j == 0) {
      float fv = wvv[0];
      int fk = wkk[0];
#pragma unroll
      for (int i = 1; i < 4; i++)
        if (wvv[i] > fv || (wvv[i] == fv && wkk[i] < fk)) { fv = wvv[i]; fk = wkk[i]; }
      selk[r] = fk;
      mag2[fk] = -2.0f;
    }
    __syncthreads();
  }
  if (j < KSEL) {
    const int k = selk[j];
    const float re = xre[k], im = xim[k];
    float* o = comp + (size_t)bd * 24 + j * 3;
    o[0] = 2.0f * sqrtf(re * re + im * im) * (1.0f / 1024.0f);
    o[1] = (float)k;
    o[2] = atan2f(im, re);
  }
}

// ---------------- season synthesis + res1 = res - season ----------------
__global__ __launch_bounds__(512) void k_season(const float* __restrict__ comp, const float* __restrict__ res,
                                                float* __restrict__ season, bf16* __restrict__ res1b,
                                                bf16* __restrict__ seasb) {
  const int d = threadIdx.x;
  const int b = blockIdx.y;
  const int t0 = blockIdx.x * 5;
  float a_[8], kf_[8], ph_[8];
  const float* c = comp + ((size_t)b * 512 + d) * 24;
#pragma unroll
  for (int i = 0; i < 8; i++) { a_[i] = c[3 * i]; kf_[i] = c[3 * i + 1]; ph_[i] = c[3 * i + 2]; }
#pragma unroll
  for (int tt = 0; tt < 5; ++tt) {
    const int t = t0 + tt;
    float acc = 0.0f;
#pragma unroll
    for (int i = 0; i < 8; i++) {
      float fr = kf_[i] * (float)t * (1.0f / 1024.0f);
      fr -= floorf(fr);
      acc += a_[i] * __cosf(fmaf(6.283185307179586f, fr, ph_[i]));
    }
    season[((size_t)b * TP + t) * D_ + d] = acc;
    if (t < T_) {
      const float rr = res[((size_t)b * T_ + t) * D_ + d] - acc;
      res1b[((size_t)b * T_ + t) * D_ + d] = __float2bfloat16(rr);
      seasb[((size_t)b * T_ + t) * D_ + d] = __float2bfloat16(acc);
    }
  }
}

// ---------------- fused f32 -> bf16 for all 6 weight tensors ----------------
#define CVT_TOTAL 2686976
__global__ __launch_bounds__(256) void k_cvt_all(const float* __restrict__ s0, const float* __restrict__ s1,
                                                 const float* __restrict__ s2_, const float* __restrict__ s3,
                                                 const float* __restrict__ s4, const float* __restrict__ s5,
                                                 bf16* __restrict__ dst) {
  const int i = (blockIdx.x * 256 + threadIdx.x) * 4;
  if (i >= CVT_TOTAL) return;
  const float* src;
  int off;
  if (i < 262144)       { src = s0;  off = i; }
  else if (i < 524288)  { src = s1;  off = i - 262144; }
  else if (i < 1572864) { src = s2_; off = i - 524288; }
  else if (i < 2621440) { src = s3;  off = i - 1572864; }
  else if (i < 2654208) { src = s4;  off = i - 2621440; }
  else                  { src = s5;  off = i - 2654208; }
  const float4 v = *(const float4*)(src + off);
  bf16* o = dst + i;
  o[0] = __float2bfloat16(v.x); o[1] = __float2bfloat16(v.y);
  o[2] = __float2bfloat16(v.z); o[3] = __float2bfloat16(v.w);
}

// ---------------- growth exp-smooth blocked scan ----------------
__global__ __launch_bounds__(1024) void k_growth_scan2(const float* __restrict__ v, const float* __restrict__ z0,
                                                       const float* __restrict__ sw, const float* __restrict__ v0,
                                                       bf16* __restrict__ s2) {
  const int b = blockIdx.x >> 3;
  const int col = (blockIdx.x & 7) * 64 + (threadIdx.x & 63);
  const int w = threadIdx.x >> 6;
  const float alpha = 1.0f / (1.0f + expf(-sw[col >> 6]));
  const float om = 1.0f - alpha;
  float a64 = alpha;
#pragma unroll
  for (int i = 0; i < 6; i++) a64 *= a64;
  const float* vp = v + (size_t)b * T_ * D_ + col;
  float vprev = (w == 0) ? z0[col] : vp[(size_t)(64 * w - 1) * D_];
  float sloc = 0.0f;
#pragma unroll 8
  for (int j = 0; j < 64; j++) {
    const float nv = vp[(size_t)(64 * w + j) * D_];
    sloc = alpha * sloc + om * (nv - vprev);
    vprev = nv;
  }
  __shared__ float lb[16][64], lc[16][64];
  lb[w][threadIdx.x & 63] = sloc;
  __syncthreads();
  if (w == 0) {
    float s = v0[col];
#pragma unroll
    for (int k = 0; k < 16; k++) { lc[k][threadIdx.x & 63] = s; s = a64 * s + lb[k][threadIdx.x & 63]; }
  }
  __syncthreads();
  float s = lc[w][threadIdx.x & 63];
  vprev = (w == 0) ? z0[col] : vp[(size_t)(64 * w - 1) * D_];
  bf16* op = s2 + (size_t)b * (T_ + 1) * D_ + col;
  if (w == 0) op[0] = __float2bfloat16(v0[col]);
#pragma unroll 8
  for (int j = 0; j < 64; j++) {
    const float nv = vp[(size_t)(64 * w + j) * D_];
    s = alpha * s + om * (nv - vprev);
    vprev = nv;
    op[(size_t)(64 * w + j + 1) * D_] = __float2bfloat16(s);
  }
}

// ---------------- level exp-smooth blocked scan ----------------
__global__ __launch_bounds__(1024) void k_level_scan2(const float* __restrict__ level, const float* __restrict__ gp,
                                                      const float* __restrict__ sp, const float* __restrict__ sw,
                                                      const float* __restrict__ v0, float* __restrict__ out) {
  const int b = blockIdx.x;
  const int w = threadIdx.x >> 6;
  const int c = threadIdx.x & 63;
  const float alpha = 1.0f / (1.0f + expf(-sw[c]));
  const float om = 1.0f - alpha;
  float a64 = alpha;
#pragma unroll
  for (int i = 0; i < 6; i++) a64 *= a64;
  const size_t base = ((size_t)b * T_ + 64 * w) * CO + c;
  float sloc = 0.0f;
#pragma unroll 8
  for (int j = 0; j < 64; j++) {
    const size_t idx = base + (size_t)j * CO;
    const float u = om * (level[idx] - sp[idx]) + alpha * gp[idx];
    out[idx] = u;
    sloc = alpha * sloc + u;
  }
  __shared__ float lb[16][64], lc[16][64];
  lb[w][c] = sloc;
  __syncthreads();
  if (w == 0) {
    float s = v0[c];
#pragma unroll
    for (int k = 0; k < 16; k++) { lc[k][c] = s; s = a64 * s + lb[k][c]; }
  }
  __syncthreads();
  float s = lc[w][c];
#pragma unroll 8
  for (int j = 0; j < 64; j++) {
    const size_t idx = base + (size_t)j * CO;
    s = alpha * s + out[idx];
    out[idx] = s;
  }
}

// ---------------- layer norm over D=512 ----------------
template <int MODE>
__global__ __launch_bounds__(128) void k_ln(const float* __restrict__ x1, const float* __restrict__ x2,
                                            const float* __restrict__ x3, const float* __restrict__ g,
                                            const float* __restrict__ be, float* __restrict__ outF,
                                            bf16* __restrict__ outB) {
  const int m = blockIdx.x, tid = threadIdx.x;
  const int b = m >> 10;
  float4 v = ((const float4*)(x1 + (size_t)m * D_))[tid];
  if (MODE == 0) {
    const float4 se = ((const float4*)(x2 + ((size_t)(m + b * PRED)) * D_))[tid];
    const float4 gr = ((const float4*)(x3 + ((size_t)(m + b + 1)) * D_))[tid];
    v.x -= se.x + gr.x; v.y -= se.y + gr.y; v.z -= se.z + gr.z; v.w -= se.w + gr.w;
  }
  float s = v.x + v.y + v.z + v.w;
  float s2 = v.x * v.x + v.y * v.y + v.z * v.z + v.w * v.w;
#pragma unroll
  for (int off = 32; off; off >>= 1) { s += __shfl_down(s, off); s2 += __shfl_down(s2, off); }
  __shared__ float p1[2], p2[2];
  if ((tid & 63) == 0) { p1[tid >> 6] = s; p2[tid >> 6] = s2; }
  __syncthreads();
  const float S = p1[0] + p1[1], S2 = p2[0] + p2[1];
  const float mu = S * (1.0f / 512.0f);
  const float rs = rsqrtf(fmaxf(S2 * (1.0f / 512.0f) - mu * mu, 0.0f) + 1e-5f);
  const float4 gg = ((const float4*)g)[tid], bb = ((const float4*)be)[tid];
  float4 o;
  o.x = (v.x - mu) * rs * gg.x + bb.x;
  o.y = (v.y - mu) * rs * gg.y + bb.y;
  o.z = (v.z - mu) * rs * gg.z + bb.z;
  o.w = (v.w - mu) * rs * gg.w + bb.w;
  ((float4*)(outF + (size_t)m * D_))[tid] = o;
  if (MODE == 0) {
    bf16* ob = outB + (size_t)m * D_ + tid * 4;
    ob[0] = __float2bfloat16(o.x); ob[1] = __float2bfloat16(o.y);
    ob[2] = __float2bfloat16(o.z); ob[3] = __float2bfloat16(o.w);
  }
}

// ---------------- bf16 MFMA GEMM, swizzled LDS (bank-conflict-free reads) ----------------
// One gload_lds16 call stages 64 lanes x 16B = 1024B = 512/BK rows (RPC).
// LDS layout (both-sides swizzle; gload dest linear, global source pre-permuted):
//  BK=64: group = 8 rows x 128B; slot cs of row rr holds global chunk (cs ^ rr)
//  BK=32: group = 16 rows; superrow sr = row pair (128B); slot cs holds idx = cs ^ (sr&7),
//         where idx = (row_in_pair<<2) | chunk
template <int BM, int BN, int BK, int EPI>
__global__ __launch_bounds__(256) void k_gemm(const bf16* __restrict__ A, const bf16* __restrict__ Bw,
                                              const float* __restrict__ bias, float* outF, bf16* __restrict__ outB,
                                              const float* resid, const int M, const int N, const int K,
                                              const int extra) {
  constexpr int WC = (BN >= 128) ? 2 : 1;
  constexpr int WR = 4 / WC;
  constexpr int FM = BM / (WR * 16);
  constexpr int FN = BN / (WC * 16);
  constexpr int RPC = 512 / BK;        // rows staged per gload-call: 1024B / (2*BK B per row)
  constexpr int LA = (BM / RPC) / 4, LB = (BN / RPC) / 4;
  constexpr int KK = BK / 32;
  static_assert(LA >= 1 && LB >= 1, "tile too small for staging split");
  __shared__ bf16 lsA[2][BM * BK];
  __shared__ bf16 lsB[2][BN * BK];
  const int tid = threadIdx.x;
  const int w = tid >> 6, lane = tid & 63;
  const int tn = blockIdx.x, tm = blockIdx.y;
  const int wr = w / WC, wc = w % WC;
  const int r16 = lane & 15, hi = lane >> 4;

  // staging lane decode (inverse swizzle on the global source)
  int srowoff, scoloff;
  if constexpr (BK == 64) {
    const int rr = lane >> 3, cs = lane & 7;
    srowoff = rr;                 // 8 rows per call
    scoloff = (cs ^ rr) * 8;
  } else {
    const int sr = lane >> 3, cs = lane & 7;
    const int idx = cs ^ (sr & 7);
    srowoff = sr * 2 + (idx >> 2);  // 16 rows per call
    scoloff = (idx & 3) * 8;
  }

  const f32x4 fzero = {0.f, 0.f, 0.f, 0.f};
  f32x4 acc[FM][FN];
#pragma unroll
  for (int i = 0; i < FM; i++)
#pragma unroll
    for (int jj = 0; jj < FN; jj++) acc[i][jj] = fzero;

  const int NT = K / BK;

  auto stage = [&](int kt, int sel) {
#pragma unroll
    for (int q = 0; q < LA; q++) {
      const int g = w * LA + q;
      int m = tm * BM + g * RPC + srowoff;
      if (m > M - 1) m = M - 1;
      m += (m >> 10) * extra;
      gload_lds16(A + (size_t)m * K + (size_t)kt * BK + scoloff, &lsA[sel][g * 512]);
    }
#pragma unroll
    for (int q = 0; q < LB; q++) {
      const int g = w * LB + q;
      const int n = tn * BN + g * RPC + srowoff;
      gload_lds16(Bw + (size_t)n * K + (size_t)kt * BK + scoloff, &lsB[sel][g * 512]);
    }
  };

  // swizzled fragment read: row = logical row in tile, cc = 16B chunk index within BK row
  auto frag = [&](const bf16* ls, int row, int cc) -> bf16x8 {
    if constexpr (BK == 64) {
      const int g = row >> 3, rr = row & 7;
      return *(const bf16x8*)&ls[g * 512 + rr * 64 + ((cc ^ rr) << 3)];
    } else {
      const int g = row >> 4, rr = row & 15, sr = rr >> 1;
      const int idx = ((rr & 1) << 2) | cc;
      return *(const bf16x8*)&ls[g * 512 + sr * 64 + ((idx ^ (sr & 7)) << 3)];
    }
  };

  stage(0, 0);
  __syncthreads();
  for (int kt = 0; kt < NT; ++kt) {
    const int sel = kt & 1;
    if (kt + 1 < NT) stage(kt + 1, sel ^ 1);
#pragma unroll
    for (int kk = 0; kk < KK; ++kk) {
      bf16x8 af[FM], bfv[FN];
#pragma unroll
      for (int i = 0; i < FM; i++)
        af[i] = frag(lsA[sel], wr * (FM * 16) + i * 16 + r16, kk * 4 + hi);
#pragma unroll
      for (int jj = 0; jj < FN; jj++)
        bfv[jj] = frag(lsB[sel], wc * (FN * 16) + jj * 16 + r16, kk * 4 + hi);
#pragma unroll
      for (int i = 0; i < FM; i++)
#pragma unroll
        for (int jj = 0; jj < FN; jj++)
          acc[i][jj] = __builtin_amdgcn_mfma_f32_16x16x32_bf16(af[i], bfv[jj], acc[i][jj], 0, 0, 0);
    }
    __syncthreads();
  }

#pragma unroll
  for (int i = 0; i < FM; i++) {
#pragma unroll
    for (int r = 0; r < 4; r++) {
      const int m = tm * BM + wr * (FM * 16) + i * 16 + hi * 4 + r;
      if (m < M) {
#pragma unroll
        for (int jj = 0; jj < FN; jj++) {
          const int n = tn * BN + wc * (FN * 16) + jj * 16 + r16;
          float x = acc[i][jj][r];
          if (bias) x += bias[n];
          const size_t idx = (size_t)m * N + n;
          if (EPI == 0) {
            outF[idx] = x;
          } else if (EPI == 1) {
            outF[idx] = x;
            outB[idx] = __float2bfloat16(x);
          } else if (EPI == 2) {
            outB[idx] = __float2bfloat16(1.0f / (1.0f + __expf(-x)));
          } else {
            outF[idx] = x + resid[idx];
          }
        }
      }
    }
  }
}

// ---------------- workspace layout ----------------
#define MB (size_t)(1u << 20)
static const size_t OFF_A = 0;
static const size_t OFF_C = 32 * MB;
static const size_t OFF_D = 40 * MB;
static const size_t OFF_E = 48 * MB;
static const size_t OFF_F = 54 * MB;
static const size_t OFF_G = 63 * MB;
static const size_t OFF_H = 72 * MB;
static const size_t OFF_J = 88 * MB;
static const size_t OFF_K = 89 * MB;
static const size_t OFF_K2 = 91 * MB;

#define W_IN 0
#define W_OUT 262144
#define W_FF1 524288
#define W_FF2 1572864
#define W_GW 2621440
#define W_SW2 2654208

extern "C" void kernel_launch(void* const* d_in, const int* in_sizes, int n_in, void* d_out, int out_size,
                              void* d_ws, size_t ws_size, hipStream_t stream) {
  (void)in_sizes; (void)n_in; (void)out_size; (void)ws_size;
  const float* res = (const float*)d_in[0];
  const float* level = (const float*)d_in[1];
  const float* gl_z0 = (const float*)d_in[2];
  const float* gl_in_w = (const float*)d_in[3];
  const float* gl_in_b = (const float*)d_in[4];
  const float* gl_sw = (const float*)d_in[5];
  const float* gl_v0 = (const float*)d_in[6];
  const float* gl_out_w = (const float*)d_in[7];
  const float* gl_out_b = (const float*)d_in[8];
  const float* ll_sw = (const float*)d_in[9];
  const float* ll_v0 = (const float*)d_in[10];
  const float* ll_gw = (const float*)d_in[11];
  const float* ll_gb = (const float*)d_in[12];
  const float* ll_sw2 = (const float*)d_in[13];
  const float* ll_sb = (const float*)d_in[14];
  const float* ff_w1 = (const float*)d_in[15];
  const float* ff_w2 = (const float*)d_in[16];
  const float* n1_g = (const float*)d_in[17];
  const float* n1_b = (const float*)d_in[18];
  const float* n2_g = (const float*)d_in[19];
  const float* n2_b = (const float*)d_in[20];

  char* ws = (char*)d_ws;
  float* resT = (float*)(ws + OFF_A);
  float* vbuf = (float*)(ws + OFF_A);
  bf16* hbuf = (bf16*)(ws + OFF_A);
  bf16* res1b = (bf16*)(ws + OFF_C);
  bf16* res2b = (bf16*)(ws + OFF_C);
  bf16* seasb = (bf16*)(ws + OFF_D);
  bf16* wE = (bf16*)(ws + OFF_E);
  bf16* s2b = (bf16*)(ws + OFF_F);
  bf16* grob = (bf16*)(ws + OFF_G);
  float* res2f = (float*)(ws + OFF_H);
  float* comp = (float*)(ws + OFF_J);
  float* gproj = (float*)(ws + OFF_K);
  float* sproj = (float*)(ws + OFF_K2);

  float* o_res = (float*)d_out;
  float* o_level = o_res + 4194304;
  float* o_growth = o_level + 524288;
  float* o_season = o_growth + 4198400;

  k_transpose<<<dim3(16, 32, 8), dim3(32, 8), 0, stream>>>(res, resT);
  k_fft_topk<<<4096, 256, 0, stream>>>(resT, comp);
  k_season<<<dim3(256, 8), 512, 0, stream>>>(comp, res, o_season, res1b, seasb);
  k_cvt_all<<<(CVT_TOTAL / 4 + 255) / 256, 256, 0, stream>>>(gl_in_w, gl_out_w, ff_w1, ff_w2, ll_gw, ll_sw2, wE);
  k_gemm<128, 128, 64, 0><<<dim3(4, 64), 256, 0, stream>>>(res1b, wE + W_IN, gl_in_b, vbuf, nullptr, nullptr, 8192, 512, 512, 0);
  k_growth_scan2<<<64, 1024, 0, stream>>>(vbuf, gl_z0, gl_sw, gl_v0, s2b);
  k_gemm<128, 128, 64, 1><<<dim3(4, 65), 256, 0, stream>>>(s2b, wE + W_OUT, gl_out_b, o_growth, grob, nullptr, 8200, 512, 512, 0);
  k_ln<0><<<8192, 128, 0, stream>>>(res, o_season, o_growth, n1_g, n1_b, res2f, res2b);
  k_gemm<128, 128, 64, 2><<<dim3(16, 64), 256, 0, stream>>>(res2b, wE + W_FF1, nullptr, nullptr, hbuf, nullptr, 8192, 2048, 512, 0);
  k_gemm<128, 128, 64, 3><<<dim3(4, 64), 256, 0, stream>>>(hbuf, wE + W_FF2, nullptr, res2f, nullptr, res2f, 8192, 512, 2048, 0);
  k_ln<1><<<8192, 128, 0, stream>>>(res2f, nullptr, nullptr, n2_g, n2_b, o_res, nullptr);
  k_gemm<128, 64, 32, 0><<<dim3(1, 64), 256, 0, stream>>>(grob, wE + W_GW, ll_gb, gproj, nullptr, nullptr, 8192, 64, 512, 1);
  k_gemm<128, 64, 32, 0><<<dim3(1, 64), 256, 0, stream>>>(seasb, wE + W_SW2, ll_sb, sproj, nullptr, nullptr, 8192, 64, 512, 0);
  k_level_scan2<<<8, 1024, 0, stream>>>(level, gproj, sproj, ll_sw, ll_v0, o_level);
}

// Round 8
// 244.821 us; speedup vs baseline: 1.4796x; 1.1141x over previous
//
#include <hip/hip_runtime.h>
#include <hip/hip_bf16.h>
#include <math.h>

#define B_ 8
#define T_ 1024
#define D_ 512
#define PRED 256
#define TP (T_ + PRED)
#define NH 8
#define DH 64
#define DFF 2048
#define CO 64
#define KSEL 8

typedef __hip_bfloat16 bf16;
using bf16x8 = __attribute__((ext_vector_type(8))) short;
using f32x4  = __attribute__((ext_vector_type(4))) float;

__device__ __forceinline__ void gload_lds16(const void* gp, void* lp) {
  __builtin_amdgcn_global_load_lds(
      (const __attribute__((address_space(1))) void*)gp,
      (__attribute__((address_space(3))) void*)lp, 16, 0, 0);
}

// ---------------- transpose res (b,T,D) -> resT (b,D,T) ----------------
__global__ __launch_bounds__(256) void k_transpose(const float* __restrict__ in, float* __restrict__ out) {
  __shared__ float tile[32][33];
  const int b = blockIdx.z;
  const int d0 = blockIdx.x * 32, t0 = blockIdx.y * 32;
  const int tx = threadIdx.x, ty = threadIdx.y;
  const float* src = in + ((size_t)b * T_ + t0) * D_ + d0;
#pragma unroll
  for (int i = 0; i < 32; i += 8) tile[ty + i][tx] = src[(size_t)(ty + i) * D_ + tx];
  __syncthreads();
  float* dst = out + ((size_t)b * D_ + d0) * T_ + t0;
#pragma unroll
  for (int i = 0; i < 32; i += 8) dst[(size_t)(ty + i) * T_ + tx] = tile[tx][ty + i];
}

// ---------------- 1024-pt real FFT per (b,d) + top-8 bins ----------------
__global__ __launch_bounds__(256) void k_fft_topk(const float* __restrict__ xt, float* __restrict__ comp) {
  __shared__ float2 bA[512], bB[512], tw[256];
  __shared__ float xre[512], xim[512], mag2[512];
  __shared__ float wvv[4];
  __shared__ int wkk[4];
  __shared__ int selk[KSEL];
  const int j = threadIdx.x;
  const int bd = blockIdx.x;
  {
    float ang = -(6.283185307179586f / 512.0f) * (float)j;
    float sn, cs;
    sincosf(ang, &sn, &cs);
    tw[j] = make_float2(cs, sn);
  }
  const float4 v4 = ((const float4*)(xt + (size_t)bd * 1024))[j];
  bA[2 * j] = make_float2(v4.x, v4.y);
  bA[2 * j + 1] = make_float2(v4.z, v4.w);
  __syncthreads();
#pragma unroll
  for (int st = 0; st < 9; ++st) {
    const int s = 1 << st;
    const int p = j >> st;
    const int q = j & (s - 1);
    const int m = 256 >> st;
    float2 a, b2;
    if ((st & 1) == 0) { a = bA[q + s * p]; b2 = bA[q + s * (p + m)]; }
    else               { a = bB[q + s * p]; b2 = bB[q + s * (p + m)]; }
    const float2 w = tw[p << st];
    float2 d0 = make_float2(a.x + b2.x, a.y + b2.y);
    const float ex = a.x - b2.x, ey = a.y - b2.y;
    float2 d1 = make_float2(ex * w.x - ey * w.y, ex * w.y + ey * w.x);
    if ((st & 1) == 0) { bB[q + s * 2 * p] = d0; bB[q + s * (2 * p + 1)] = d1; }
    else               { bA[q + s * 2 * p] = d0; bA[q + s * (2 * p + 1)] = d1; }
    __syncthreads();
  }
#pragma unroll
  for (int u = 0; u < 2; ++u) {
    const int k = (u == 0) ? (j + 1) : (j + 257);
    if (k <= 511) {
      const float2 zk = bB[k & 511];
      const float2 zm = bB[(512 - k) & 511];
      const float Ex = 0.5f * (zk.x + zm.x), Ey = 0.5f * (zk.y - zm.y);
      const float Ox = 0.5f * (zk.y + zm.y), Oy = 0.5f * (zm.x - zk.x);
      float sn, cs;
      sincosf(-(6.283185307179586f / 1024.0f) * (float)k, &sn, &cs);
      const float Xr = Ex + cs * Ox - sn * Oy;
      const float Xi = Ey + cs * Oy + sn * Ox;
      xre[k] = Xr; xim[k] = Xi; mag2[k] = Xr * Xr + Xi * Xi;
    }
  }
  if (j == 0) mag2[0] = -1.0f;
  __syncthreads();
  const int lane = j & 63, wvi = j >> 6;
  for (int r = 0; r < KSEL; ++r) {
    float bv = mag2[j];
    int bk = j;
    const float v2 = mag2[j + 256];
    if (v2 > bv) { bv = v2; bk = j + 256; }
#pragma unroll
    for (int off = 32; off; off >>= 1) {
      const float ov = __shfl_down(bv, off);
      const int ok = __shfl_down(bk, off);
      if (ov > bv || (ov == bv && ok < bk)) { bv = ov; bk = ok; }
    }
    if (lane == 0) { wvv[wvi] = bv; wkk[wvi] = bk; }
    __syncthreads();
    if (j == 0) {
      float fv = wvv[0];
      int fk = wkk[0];
#pragma unroll
      for (int i = 1; i < 4; i++)
        if (wvv[i] > fv || (wvv[i] == fv && wkk[i] < fk)) { fv = wvv[i]; fk = wkk[i]; }
      selk[r] = fk;
      mag2[fk] = -2.0f;
    }
    __syncthreads();
  }
  if (j < KSEL) {
    const int k = selk[j];
    const float re = xre[k], im = xim[k];
    float* o = comp + (size_t)bd * 24 + j * 3;
    o[0] = 2.0f * sqrtf(re * re + im * im) * (1.0f / 1024.0f);
    o[1] = (float)k;
    o[2] = atan2f(im, re);
  }
}

// ---------------- season synthesis + res1 = res - season ----------------
__global__ __launch_bounds__(512) void k_season(const float* __restrict__ comp, const float* __restrict__ res,
                                                float* __restrict__ season, bf16* __restrict__ res1b,
                                                bf16* __restrict__ seasb) {
  const int d = threadIdx.x;
  const int b = blockIdx.y;
  const int t0 = blockIdx.x * 5;
  float a_[8], kf_[8], ph_[8];
  const float* c = comp + ((size_t)b * 512 + d) * 24;
#pragma unroll
  for (int i = 0; i < 8; i++) { a_[i] = c[3 * i]; kf_[i] = c[3 * i + 1]; ph_[i] = c[3 * i + 2]; }
#pragma unroll
  for (int tt = 0; tt < 5; ++tt) {
    const int t = t0 + tt;
    float acc = 0.0f;
#pragma unroll
    for (int i = 0; i < 8; i++) {
      float fr = kf_[i] * (float)t * (1.0f / 1024.0f);
      fr -= floorf(fr);
      acc += a_[i] * __cosf(fmaf(6.283185307179586f, fr, ph_[i]));
    }
    season[((size_t)b * TP + t) * D_ + d] = acc;
    if (t < T_) {
      const float rr = res[((size_t)b * T_ + t) * D_ + d] - acc;
      res1b[((size_t)b * T_ + t) * D_ + d] = __float2bfloat16(rr);
      seasb[((size_t)b * T_ + t) * D_ + d] = __float2bfloat16(acc);
    }
  }
}

// ---------------- fused f32 -> bf16 for all 6 weight tensors ----------------
#define CVT_TOTAL 2686976
__global__ __launch_bounds__(256) void k_cvt_all(const float* __restrict__ s0, const float* __restrict__ s1,
                                                 const float* __restrict__ s2_, const float* __restrict__ s3,
                                                 const float* __restrict__ s4, const float* __restrict__ s5,
                                                 bf16* __restrict__ dst) {
  const int i = (blockIdx.x * 256 + threadIdx.x) * 4;
  if (i >= CVT_TOTAL) return;
  const float* src;
  int off;
  if (i < 262144)       { src = s0;  off = i; }
  else if (i < 524288)  { src = s1;  off = i - 262144; }
  else if (i < 1572864) { src = s2_; off = i - 524288; }
  else if (i < 2621440) { src = s3;  off = i - 1572864; }
  else if (i < 2654208) { src = s4;  off = i - 2621440; }
  else                  { src = s5;  off = i - 2654208; }
  const float4 v = *(const float4*)(src + off);
  bf16* o = dst + i;
  o[0] = __float2bfloat16(v.x); o[1] = __float2bfloat16(v.y);
  o[2] = __float2bfloat16(v.z); o[3] = __float2bfloat16(v.w);
}

// ---------------- growth exp-smooth blocked scan ----------------
__global__ __launch_bounds__(1024) void k_growth_scan2(const float* __restrict__ v, const float* __restrict__ z0,
                                                       const float* __restrict__ sw, const float* __restrict__ v0,
                                                       bf16* __restrict__ s2) {
  const int b = blockIdx.x >> 3;
  const int col = (blockIdx.x & 7) * 64 + (threadIdx.x & 63);
  const int w = threadIdx.x >> 6;
  const float alpha = 1.0f / (1.0f + expf(-sw[col >> 6]));
  const float om = 1.0f - alpha;
  float a64 = alpha;
#pragma unroll
  for (int i = 0; i < 6; i++) a64 *= a64;
  const float* vp = v + (size_t)b * T_ * D_ + col;
  float vprev = (w == 0) ? z0[col] : vp[(size_t)(64 * w - 1) * D_];
  float sloc = 0.0f;
#pragma unroll 8
  for (int j = 0; j < 64; j++) {
    const float nv = vp[(size_t)(64 * w + j) * D_];
    sloc = alpha * sloc + om * (nv - vprev);
    vprev = nv;
  }
  __shared__ float lb[16][64], lc[16][64];
  lb[w][threadIdx.x & 63] = sloc;
  __syncthreads();
  if (w == 0) {
    float s = v0[col];
#pragma unroll
    for (int k = 0; k < 16; k++) { lc[k][threadIdx.x & 63] = s; s = a64 * s + lb[k][threadIdx.x & 63]; }
  }
  __syncthreads();
  float s = lc[w][threadIdx.x & 63];
  vprev = (w == 0) ? z0[col] : vp[(size_t)(64 * w - 1) * D_];
  bf16* op = s2 + (size_t)b * (T_ + 1) * D_ + col;
  if (w == 0) op[0] = __float2bfloat16(v0[col]);
#pragma unroll 8
  for (int j = 0; j < 64; j++) {
    const float nv = vp[(size_t)(64 * w + j) * D_];
    s = alpha * s + om * (nv - vprev);
    vprev = nv;
    op[(size_t)(64 * w + j + 1) * D_] = __float2bfloat16(s);
  }
}

// ---------------- level exp-smooth blocked scan ----------------
__global__ __launch_bounds__(1024) void k_level_scan2(const float* __restrict__ level, const float* __restrict__ gp,
                                                      const float* __restrict__ sp, const float* __restrict__ sw,
                                                      const float* __restrict__ v0, float* __restrict__ out) {
  const int b = blockIdx.x;
  const int w = threadIdx.x >> 6;
  const int c = threadIdx.x & 63;
  const float alpha = 1.0f / (1.0f + expf(-sw[c]));
  const float om = 1.0f - alpha;
  float a64 = alpha;
#pragma unroll
  for (int i = 0; i < 6; i++) a64 *= a64;
  const size_t base = ((size_t)b * T_ + 64 * w) * CO + c;
  float sloc = 0.0f;
#pragma unroll 8
  for (int j = 0; j < 64; j++) {
    const size_t idx = base + (size_t)j * CO;
    const float u = om * (level[idx] - sp[idx]) + alpha * gp[idx];
    out[idx] = u;
    sloc = alpha * sloc + u;
  }
  __shared__ float lb[16][64], lc[16][64];
  lb[w][c] = sloc;
  __syncthreads();
  if (w == 0) {
    float s = v0[c];
#pragma unroll
    for (int k = 0; k < 16; k++) { lc[k][c] = s; s = a64 * s + lb[k][c]; }
  }
  __syncthreads();
  float s = lc[w][c];
#pragma unroll 8
  for (int j = 0; j < 64; j++) {
    const size_t idx = base + (size_t)j * CO;
    s = alpha * s + out[idx];
    out[idx] = s;
  }
}

// ---------------- layer norm over D=512 ----------------
template <int MODE>
__global__ __launch_bounds__(128) void k_ln(const float* __restrict__ x1, const float* __restrict__ x2,
                                            const float* __restrict__ x3, const float* __restrict__ g,
                                            const float* __restrict__ be, float* __restrict__ outF,
                                            bf16* __restrict__ outB) {
  const int m = blockIdx.x, tid = threadIdx.x;
  const int b = m >> 10;
  float4 v = ((const float4*)(x1 + (size_t)m * D_))[tid];
  if (MODE == 0) {
    const float4 se = ((const float4*)(x2 + ((size_t)(m + b * PRED)) * D_))[tid];
    const float4 gr = ((const float4*)(x3 + ((size_t)(m + b + 1)) * D_))[tid];
    v.x -= se.x + gr.x; v.y -= se.y + gr.y; v.z -= se.z + gr.z; v.w -= se.w + gr.w;
  }
  float s = v.x + v.y + v.z + v.w;
  float s2 = v.x * v.x + v.y * v.y + v.z * v.z + v.w * v.w;
#pragma unroll
  for (int off = 32; off; off >>= 1) { s += __shfl_down(s, off); s2 += __shfl_down(s2, off); }
  __shared__ float p1[2], p2[2];
  if ((tid & 63) == 0) { p1[tid >> 6] = s; p2[tid >> 6] = s2; }
  __syncthreads();
  const float S = p1[0] + p1[1], S2 = p2[0] + p2[1];
  const float mu = S * (1.0f / 512.0f);
  const float rs = rsqrtf(fmaxf(S2 * (1.0f / 512.0f) - mu * mu, 0.0f) + 1e-5f);
  const float4 gg = ((const float4*)g)[tid], bb = ((const float4*)be)[tid];
  float4 o;
  o.x = (v.x - mu) * rs * gg.x + bb.x;
  o.y = (v.y - mu) * rs * gg.y + bb.y;
  o.z = (v.z - mu) * rs * gg.z + bb.z;
  o.w = (v.w - mu) * rs * gg.w + bb.w;
  ((float4*)(outF + (size_t)m * D_))[tid] = o;
  if (MODE == 0) {
    bf16* ob = outB + (size_t)m * D_ + tid * 4;
    ob[0] = __float2bfloat16(o.x); ob[1] = __float2bfloat16(o.y);
    ob[2] = __float2bfloat16(o.z); ob[3] = __float2bfloat16(o.w);
  }
}

// ---------------- bf16 MFMA GEMM, swizzled LDS (bank-conflict-free reads) ----------------
// One gload_lds16 call stages 64 lanes x 16B = 1024B = 512/BK rows (RPC).
// LDS layout (both-sides swizzle; gload dest linear, global source pre-permuted):
//  BK=64: group = 8 rows x 128B; slot cs of row rr holds global chunk (cs ^ rr)
//  BK=32: group = 16 rows; superrow sr = row pair (128B); slot cs holds idx = cs ^ (sr&7),
//         where idx = (row_in_pair<<2) | chunk
template <int BM, int BN, int BK, int EPI>
__global__ __launch_bounds__(256) void k_gemm(const bf16* __restrict__ A, const bf16* __restrict__ Bw,
                                              const float* __restrict__ bias, float* outF, bf16* __restrict__ outB,
                                              const float* resid, const int M, const int N, const int K,
                                              const int extra) {
  constexpr int WC = (BN >= 128) ? 2 : 1;
  constexpr int WR = 4 / WC;
  constexpr int FM = BM / (WR * 16);
  constexpr int FN = BN / (WC * 16);
  constexpr int RPC = 512 / BK;        // rows staged per gload-call: 1024B / (2*BK B per row)
  constexpr int LA = (BM / RPC) / 4, LB = (BN / RPC) / 4;
  constexpr int KK = BK / 32;
  static_assert(LA >= 1 && LB >= 1, "tile too small for staging split");
  __shared__ bf16 lsA[2][BM * BK];
  __shared__ bf16 lsB[2][BN * BK];
  const int tid = threadIdx.x;
  const int w = tid >> 6, lane = tid & 63;
  const int tn = blockIdx.x, tm = blockIdx.y;
  const int wr = w / WC, wc = w % WC;
  const int r16 = lane & 15, hi = lane >> 4;

  // staging lane decode (inverse swizzle on the global source)
  int srowoff, scoloff;
  if constexpr (BK == 64) {
    const int rr = lane >> 3, cs = lane & 7;
    srowoff = rr;                 // 8 rows per call
    scoloff = (cs ^ rr) * 8;
  } else {
    const int sr = lane >> 3, cs = lane & 7;
    const int idx = cs ^ (sr & 7);
    srowoff = sr * 2 + (idx >> 2);  // 16 rows per call
    scoloff = (idx & 3) * 8;
  }

  const f32x4 fzero = {0.f, 0.f, 0.f, 0.f};
  f32x4 acc[FM][FN];
#pragma unroll
  for (int i = 0; i < FM; i++)
#pragma unroll
    for (int jj = 0; jj < FN; jj++) acc[i][jj] = fzero;

  const int NT = K / BK;

  auto stage = [&](int kt, int sel) {
#pragma unroll
    for (int q = 0; q < LA; q++) {
      const int g = w * LA + q;
      int m = tm * BM + g * RPC + srowoff;
      if (m > M - 1) m = M - 1;
      m += (m >> 10) * extra;
      gload_lds16(A + (size_t)m * K + (size_t)kt * BK + scoloff, &lsA[sel][g * 512]);
    }
#pragma unroll
    for (int q = 0; q < LB; q++) {
      const int g = w * LB + q;
      const int n = tn * BN + g * RPC + srowoff;
      gload_lds16(Bw + (size_t)n * K + (size_t)kt * BK + scoloff, &lsB[sel][g * 512]);
    }
  };

  // swizzled fragment read: row = logical row in tile, cc = 16B chunk index within BK row
  auto frag = [&](const bf16* ls, int row, int cc) -> bf16x8 {
    if constexpr (BK == 64) {
      const int g = row >> 3, rr = row & 7;
      return *(const bf16x8*)&ls[g * 512 + rr * 64 + ((cc ^ rr) << 3)];
    } else {
      const int g = row >> 4, rr = row & 15, sr = rr >> 1;
      const int idx = ((rr & 1) << 2) | cc;
      return *(const bf16x8*)&ls[g * 512 + sr * 64 + ((idx ^ (sr & 7)) << 3)];
    }
  };

  stage(0, 0);
  __syncthreads();
  for (int kt = 0; kt < NT; ++kt) {
    const int sel = kt & 1;
    if (kt + 1 < NT) stage(kt + 1, sel ^ 1);
#pragma unroll
    for (int kk = 0; kk < KK; ++kk) {
      bf16x8 af[FM], bfv[FN];
#pragma unroll
      for (int i = 0; i < FM; i++)
        af[i] = frag(lsA[sel], wr * (FM * 16) + i * 16 + r16, kk * 4 + hi);
#pragma unroll
      for (int jj = 0; jj < FN; jj++)
        bfv[jj] = frag(lsB[sel], wc * (FN * 16) + jj * 16 + r16, kk * 4 + hi);
#pragma unroll
      for (int i = 0; i < FM; i++)
#pragma unroll
        for (int jj = 0; jj < FN; jj++)
          acc[i][jj] = __builtin_amdgcn_mfma_f32_16x16x32_bf16(af[i], bfv[jj], acc[i][jj], 0, 0, 0);
    }
    __syncthreads();
  }

#pragma unroll
  for (int i = 0; i < FM; i++) {
#pragma unroll
    for (int r = 0; r < 4; r++) {
      const int m = tm * BM + wr * (FM * 16) + i * 16 + hi * 4 + r;
      if (m < M) {
#pragma unroll
        for (int jj = 0; jj < FN; jj++) {
          const int n = tn * BN + wc * (FN * 16) + jj * 16 + r16;
          float x = acc[i][jj][r];
          if (bias) x += bias[n];
          const size_t idx = (size_t)m * N + n;
          if (EPI == 0) {
            outF[idx] = x;
          } else if (EPI == 1) {
            outF[idx] = x;
            outB[idx] = __float2bfloat16(x);
          } else if (EPI == 2) {
            outB[idx] = __float2bfloat16(1.0f / (1.0f + __expf(-x)));
          } else {
            outF[idx] = x + resid[idx];
          }
        }
      }
    }
  }
}

// ---------------- workspace layout ----------------
#define MB (size_t)(1u << 20)
static const size_t OFF_A = 0;
static const size_t OFF_C = 32 * MB;
static const size_t OFF_D = 40 * MB;
static const size_t OFF_E = 48 * MB;
static const size_t OFF_F = 54 * MB;
static const size_t OFF_G = 63 * MB;
static const size_t OFF_H = 72 * MB;
static const size_t OFF_J = 88 * MB;
static const size_t OFF_K = 89 * MB;
static const size_t OFF_K2 = 91 * MB;

#define W_IN 0
#define W_OUT 262144
#define W_FF1 524288
#define W_FF2 1572864
#define W_GW 2621440
#define W_SW2 2654208

extern "C" void kernel_launch(void* const* d_in, const int* in_sizes, int n_in, void* d_out, int out_size,
                              void* d_ws, size_t ws_size, hipStream_t stream) {
  (void)in_sizes; (void)n_in; (void)out_size; (void)ws_size;
  const float* res = (const float*)d_in[0];
  const float* level = (const float*)d_in[1];
  const float* gl_z0 = (const float*)d_in[2];
  const float* gl_in_w = (const float*)d_in[3];
  const float* gl_in_b = (const float*)d_in[4];
  const float* gl_sw = (const float*)d_in[5];
  const float* gl_v0 = (const float*)d_in[6];
  const float* gl_out_w = (const float*)d_in[7];
  const float* gl_out_b = (const float*)d_in[8];
  const float* ll_sw = (const float*)d_in[9];
  const float* ll_v0 = (const float*)d_in[10];
  const float* ll_gw = (const float*)d_in[11];
  const float* ll_gb = (const float*)d_in[12];
  const float* ll_sw2 = (const float*)d_in[13];
  const float* ll_sb = (const float*)d_in[14];
  const float* ff_w1 = (const float*)d_in[15];
  const float* ff_w2 = (const float*)d_in[16];
  const float* n1_g = (const float*)d_in[17];
  const float* n1_b = (const float*)d_in[18];
  const float* n2_g = (const float*)d_in[19];
  const float* n2_b = (const float*)d_in[20];

  char* ws = (char*)d_ws;
  float* resT = (float*)(ws + OFF_A);
  float* vbuf = (float*)(ws + OFF_A);
  bf16* hbuf = (bf16*)(ws + OFF_A);
  bf16* res1b = (bf16*)(ws + OFF_C);
  bf16* res2b = (bf16*)(ws + OFF_C);
  bf16* seasb = (bf16*)(ws + OFF_D);
  bf16* wE = (bf16*)(ws + OFF_E);
  bf16* s2b = (bf16*)(ws + OFF_F);
  bf16* grob = (bf16*)(ws + OFF_G);
  float* res2f = (float*)(ws + OFF_H);
  float* comp = (float*)(ws + OFF_J);
  float* gproj = (float*)(ws + OFF_K);
  float* sproj = (float*)(ws + OFF_K2);

  float* o_res = (float*)d_out;
  float* o_level = o_res + 4194304;
  float* o_growth = o_level + 524288;
  float* o_season = o_growth + 4198400;

  k_transpose<<<dim3(16, 32, 8), dim3(32, 8), 0, stream>>>(res, resT);
  k_fft_topk<<<4096, 256, 0, stream>>>(resT, comp);
  k_season<<<dim3(256, 8), 512, 0, stream>>>(comp, res, o_season, res1b, seasb);
  k_cvt_all<<<(CVT_TOTAL / 4 + 255) / 256, 256, 0, stream>>>(gl_in_w, gl_out_w, ff_w1, ff_w2, ll_gw, ll_sw2, wE);
  // v = res1 @ gl_in_w^T + b       (64x128 tile, BK=64: grid 512 -> 2 blocks/CU)
  k_gemm<64, 128, 64, 0><<<dim3(4, 128), 256, 0, stream>>>(res1b, wE + W_IN, gl_in_b, vbuf, nullptr, nullptr, 8192, 512, 512, 0);
  k_growth_scan2<<<64, 1024, 0, stream>>>(vbuf, gl_z0, gl_sw, gl_v0, s2b);
  // growth = s2 @ gl_out_w^T + b   (M=8200 -> 129 row tiles)
  k_gemm<64, 128, 64, 1><<<dim3(4, 129), 256, 0, stream>>>(s2b, wE + W_OUT, gl_out_b, o_growth, grob, nullptr, 8200, 512, 512, 0);
  k_ln<0><<<8192, 128, 0, stream>>>(res, o_season, o_growth, n1_g, n1_b, res2f, res2b);
  // FF1: 128x128 BK=32 (32KB LDS): grid 1024 -> 4 blocks/CU (m97/m103-verified occupancy regime)
  k_gemm<128, 128, 32, 2><<<dim3(16, 64), 256, 0, stream>>>(res2b, wE + W_FF1, nullptr, nullptr, hbuf, nullptr, 8192, 2048, 512, 0);
  // FF2: 64x128 BK=64: grid 512 -> 2 blocks/CU
  k_gemm<64, 128, 64, 3><<<dim3(4, 128), 256, 0, stream>>>(hbuf, wE + W_FF2, nullptr, res2f, nullptr, res2f, 8192, 512, 2048, 0);
  k_ln<1><<<8192, 128, 0, stream>>>(res2f, nullptr, nullptr, n2_g, n2_b, o_res, nullptr);
  // gproj/sproj: 64x64 BK=64: grid 128 each
  k_gemm<64, 64, 64, 0><<<dim3(1, 128), 256, 0, stream>>>(grob, wE + W_GW, ll_gb, gproj, nullptr, nullptr, 8192, 64, 512, 1);
  k_gemm<64, 64, 64, 0><<<dim3(1, 128), 256, 0, stream>>>(seasb, wE + W_SW2, ll_sb, sproj, nullptr, nullptr, 8192, 64, 512, 0);
  k_level_scan2<<<8, 1024, 0, stream>>>(level, gproj, sproj, ll_sw, ll_v0, o_level);
}

// Round 9
// 243.836 us; speedup vs baseline: 1.4856x; 1.0040x over previous
//
#include <hip/hip_runtime.h>
#include <hip/hip_bf16.h>
#include <math.h>

#define B_ 8
#define T_ 1024
#define D_ 512
#define PRED 256
#define TP (T_ + PRED)
#define NH 8
#define DH 64
#define DFF 2048
#define CO 64
#define KSEL 8

typedef __hip_bfloat16 bf16;
using bf16x8 = __attribute__((ext_vector_type(8))) short;
using f32x4  = __attribute__((ext_vector_type(4))) float;

__device__ __forceinline__ void gload_lds16(const void* gp, void* lp) {
  __builtin_amdgcn_global_load_lds(
      (const __attribute__((address_space(1))) void*)gp,
      (__attribute__((address_space(3))) void*)lp, 16, 0, 0);
}

// counted vmem wait (N = loads allowed to stay in flight)
template <int N>
__device__ __forceinline__ void vm_wait() {
  if constexpr (N == 0)      asm volatile("s_waitcnt vmcnt(0)" ::: "memory");
  else if constexpr (N == 2) asm volatile("s_waitcnt vmcnt(2)" ::: "memory");
  else if constexpr (N == 4) asm volatile("s_waitcnt vmcnt(4)" ::: "memory");
  else if constexpr (N == 6) asm volatile("s_waitcnt vmcnt(6)" ::: "memory");
  else if constexpr (N == 8) asm volatile("s_waitcnt vmcnt(8)" ::: "memory");
  else static_assert(N == 0, "unsupported vmcnt literal");
}

// ---------------- transpose res (b,T,D) -> resT (b,D,T) ----------------
__global__ __launch_bounds__(256) void k_transpose(const float* __restrict__ in, float* __restrict__ out) {
  __shared__ float tile[32][33];
  const int b = blockIdx.z;
  const int d0 = blockIdx.x * 32, t0 = blockIdx.y * 32;
  const int tx = threadIdx.x, ty = threadIdx.y;
  const float* src = in + ((size_t)b * T_ + t0) * D_ + d0;
#pragma unroll
  for (int i = 0; i < 32; i += 8) tile[ty + i][tx] = src[(size_t)(ty + i) * D_ + tx];
  __syncthreads();
  float* dst = out + ((size_t)b * D_ + d0) * T_ + t0;
#pragma unroll
  for (int i = 0; i < 32; i += 8) dst[(size_t)(ty + i) * T_ + tx] = tile[tx][ty + i];
}

// ---------------- 1024-pt real FFT per (b,d) + top-8 bins ----------------
__global__ __launch_bounds__(256) void k_fft_topk(const float* __restrict__ xt, float* __restrict__ comp) {
  __shared__ float2 bA[512], bB[512], tw[256];
  __shared__ float xre[512], xim[512], mag2[512];
  __shared__ float wvv[4];
  __shared__ int wkk[4];
  __shared__ int selk[KSEL];
  const int j = threadIdx.x;
  const int bd = blockIdx.x;
  {
    float ang = -(6.283185307179586f / 512.0f) * (float)j;
    float sn, cs;
    sincosf(ang, &sn, &cs);
    tw[j] = make_float2(cs, sn);
  }
  const float4 v4 = ((const float4*)(xt + (size_t)bd * 1024))[j];
  bA[2 * j] = make_float2(v4.x, v4.y);
  bA[2 * j + 1] = make_float2(v4.z, v4.w);
  __syncthreads();
#pragma unroll
  for (int st = 0; st < 9; ++st) {
    const int s = 1 << st;
    const int p = j >> st;
    const int q = j & (s - 1);
    const int m = 256 >> st;
    float2 a, b2;
    if ((st & 1) == 0) { a = bA[q + s * p]; b2 = bA[q + s * (p + m)]; }
    else               { a = bB[q + s * p]; b2 = bB[q + s * (p + m)]; }
    const float2 w = tw[p << st];
    float2 d0 = make_float2(a.x + b2.x, a.y + b2.y);
    const float ex = a.x - b2.x, ey = a.y - b2.y;
    float2 d1 = make_float2(ex * w.x - ey * w.y, ex * w.y + ey * w.x);
    if ((st & 1) == 0) { bB[q + s * 2 * p] = d0; bB[q + s * (2 * p + 1)] = d1; }
    else               { bA[q + s * 2 * p] = d0; bA[q + s * (2 * p + 1)] = d1; }
    __syncthreads();
  }
#pragma unroll
  for (int u = 0; u < 2; ++u) {
    const int k = (u == 0) ? (j + 1) : (j + 257);
    if (k <= 511) {
      const float2 zk = bB[k & 511];
      const float2 zm = bB[(512 - k) & 511];
      const float Ex = 0.5f * (zk.x + zm.x), Ey = 0.5f * (zk.y - zm.y);
      const float Ox = 0.5f * (zk.y + zm.y), Oy = 0.5f * (zm.x - zk.x);
      float sn, cs;
      sincosf(-(6.283185307179586f / 1024.0f) * (float)k, &sn, &cs);
      const float Xr = Ex + cs * Ox - sn * Oy;
      const float Xi = Ey + cs * Oy + sn * Ox;
      xre[k] = Xr; xim[k] = Xi; mag2[k] = Xr * Xr + Xi * Xi;
    }
  }
  if (j == 0) mag2[0] = -1.0f;
  __syncthreads();
  const int lane = j & 63, wvi = j >> 6;
  for (int r = 0; r < KSEL; ++r) {
    float bv = mag2[j];
    int bk = j;
    const float v2 = mag2[j + 256];
    if (v2 > bv) { bv = v2; bk = j + 256; }
#pragma unroll
    for (int off = 32; off; off >>= 1) {
      const float ov = __shfl_down(bv, off);
      const int ok = __shfl_down(bk, off);
      if (ov > bv || (ov == bv && ok < bk)) { bv = ov; bk = ok; }
    }
    if (lane == 0) { wvv[wvi] = bv; wkk[wvi] = bk; }
    __syncthreads();
    if (j == 0) {
      float fv = wvv[0];
      int fk = wkk[0];
#pragma unroll
      for (int i = 1; i < 4; i++)
        if (wvv[i] > fv || (wvv[i] == fv && wkk[i] < fk)) { fv = wvv[i]; fk = wkk[i]; }
      selk[r] = fk;
      mag2[fk] = -2.0f;
    }
    __syncthreads();
  }
  if (j < KSEL) {
    const int k = selk[j];
    const float re = xre[k], im = xim[k];
    float* o = comp + (size_t)bd * 24 + j * 3;
    o[0] = 2.0f * sqrtf(re * re + im * im) * (1.0f / 1024.0f);
    o[1] = (float)k;
    o[2] = atan2f(im, re);
  }
}

// ---------------- season synthesis + res1 = res - season ----------------
__global__ __launch_bounds__(512) void k_season(const float* __restrict__ comp, const float* __restrict__ res,
                                                float* __restrict__ season, bf16* __restrict__ res1b,
                                                bf16* __restrict__ seasb) {
  const int d = threadIdx.x;
  const int b = blockIdx.y;
  const int t0 = blockIdx.x * 5;
  float a_[8], kf_[8], ph_[8];
  const float* c = comp + ((size_t)b * 512 + d) * 24;
#pragma unroll
  for (int i = 0; i < 8; i++) { a_[i] = c[3 * i]; kf_[i] = c[3 * i + 1]; ph_[i] = c[3 * i + 2]; }
#pragma unroll
  for (int tt = 0; tt < 5; ++tt) {
    const int t = t0 + tt;
    float acc = 0.0f;
#pragma unroll
    for (int i = 0; i < 8; i++) {
      float fr = kf_[i] * (float)t * (1.0f / 1024.0f);
      fr -= floorf(fr);
      acc += a_[i] * __cosf(fmaf(6.283185307179586f, fr, ph_[i]));
    }
    season[((size_t)b * TP + t) * D_ + d] = acc;
    if (t < T_) {
      const float rr = res[((size_t)b * T_ + t) * D_ + d] - acc;
      res1b[((size_t)b * T_ + t) * D_ + d] = __float2bfloat16(rr);
      seasb[((size_t)b * T_ + t) * D_ + d] = __float2bfloat16(acc);
    }
  }
}

// ---------------- fused f32 -> bf16 for all 6 weight tensors ----------------
#define CVT_TOTAL 2686976
__global__ __launch_bounds__(256) void k_cvt_all(const float* __restrict__ s0, const float* __restrict__ s1,
                                                 const float* __restrict__ s2_, const float* __restrict__ s3,
                                                 const float* __restrict__ s4, const float* __restrict__ s5,
                                                 bf16* __restrict__ dst) {
  const int i = (blockIdx.x * 256 + threadIdx.x) * 4;
  if (i >= CVT_TOTAL) return;
  const float* src;
  int off;
  if (i < 262144)       { src = s0;  off = i; }
  else if (i < 524288)  { src = s1;  off = i - 262144; }
  else if (i < 1572864) { src = s2_; off = i - 524288; }
  else if (i < 2621440) { src = s3;  off = i - 1572864; }
  else if (i < 2654208) { src = s4;  off = i - 2621440; }
  else                  { src = s5;  off = i - 2654208; }
  const float4 v = *(const float4*)(src + off);
  bf16* o = dst + i;
  o[0] = __float2bfloat16(v.x); o[1] = __float2bfloat16(v.y);
  o[2] = __float2bfloat16(v.z); o[3] = __float2bfloat16(v.w);
}

// ---------------- growth exp-smooth blocked scan ----------------
__global__ __launch_bounds__(1024) void k_growth_scan2(const float* __restrict__ v, const float* __restrict__ z0,
                                                       const float* __restrict__ sw, const float* __restrict__ v0,
                                                       bf16* __restrict__ s2) {
  const int b = blockIdx.x >> 3;
  const int col = (blockIdx.x & 7) * 64 + (threadIdx.x & 63);
  const int w = threadIdx.x >> 6;
  const float alpha = 1.0f / (1.0f + expf(-sw[col >> 6]));
  const float om = 1.0f - alpha;
  float a64 = alpha;
#pragma unroll
  for (int i = 0; i < 6; i++) a64 *= a64;
  const float* vp = v + (size_t)b * T_ * D_ + col;
  float vprev = (w == 0) ? z0[col] : vp[(size_t)(64 * w - 1) * D_];
  float sloc = 0.0f;
#pragma unroll 8
  for (int j = 0; j < 64; j++) {
    const float nv = vp[(size_t)(64 * w + j) * D_];
    sloc = alpha * sloc + om * (nv - vprev);
    vprev = nv;
  }
  __shared__ float lb[16][64], lc[16][64];
  lb[w][threadIdx.x & 63] = sloc;
  __syncthreads();
  if (w == 0) {
    float s = v0[col];
#pragma unroll
    for (int k = 0; k < 16; k++) { lc[k][threadIdx.x & 63] = s; s = a64 * s + lb[k][threadIdx.x & 63]; }
  }
  __syncthreads();
  float s = lc[w][threadIdx.x & 63];
  vprev = (w == 0) ? z0[col] : vp[(size_t)(64 * w - 1) * D_];
  bf16* op = s2 + (size_t)b * (T_ + 1) * D_ + col;
  if (w == 0) op[0] = __float2bfloat16(v0[col]);
#pragma unroll 8
  for (int j = 0; j < 64; j++) {
    const float nv = vp[(size_t)(64 * w + j) * D_];
    s = alpha * s + om * (nv - vprev);
    vprev = nv;
    op[(size_t)(64 * w + j + 1) * D_] = __float2bfloat16(s);
  }
}

// ---------------- level exp-smooth blocked scan ----------------
__global__ __launch_bounds__(1024) void k_level_scan2(const float* __restrict__ level, const float* __restrict__ gp,
                                                      const float* __restrict__ sp, const float* __restrict__ sw,
                                                      const float* __restrict__ v0, float* __restrict__ out) {
  const int b = blockIdx.x;
  const int w = threadIdx.x >> 6;
  const int c = threadIdx.x & 63;
  const float alpha = 1.0f / (1.0f + expf(-sw[c]));
  const float om = 1.0f - alpha;
  float a64 = alpha;
#pragma unroll
  for (int i = 0; i < 6; i++) a64 *= a64;
  const size_t base = ((size_t)b * T_ + 64 * w) * CO + c;
  float sloc = 0.0f;
#pragma unroll 8
  for (int j = 0; j < 64; j++) {
    const size_t idx = base + (size_t)j * CO;
    const float u = om * (level[idx] - sp[idx]) + alpha * gp[idx];
    out[idx] = u;
    sloc = alpha * sloc + u;
  }
  __shared__ float lb[16][64], lc[16][64];
  lb[w][c] = sloc;
  __syncthreads();
  if (w == 0) {
    float s = v0[c];
#pragma unroll
    for (int k = 0; k < 16; k++) { lc[k][c] = s; s = a64 * s + lb[k][c]; }
  }
  __syncthreads();
  float s = lc[w][c];
#pragma unroll 8
  for (int j = 0; j < 64; j++) {
    const size_t idx = base + (size_t)j * CO;
    s = alpha * s + out[idx];
    out[idx] = s;
  }
}

// ---------------- layer norm over D=512 ----------------
template <int MODE>
__global__ __launch_bounds__(128) void k_ln(const float* __restrict__ x1, const float* __restrict__ x2,
                                            const float* __restrict__ x3, const float* __restrict__ g,
                                            const float* __restrict__ be, float* __restrict__ outF,
                                            bf16* __restrict__ outB) {
  const int m = blockIdx.x, tid = threadIdx.x;
  const int b = m >> 10;
  float4 v = ((const float4*)(x1 + (size_t)m * D_))[tid];
  if (MODE == 0) {
    const float4 se = ((const float4*)(x2 + ((size_t)(m + b * PRED)) * D_))[tid];
    const float4 gr = ((const float4*)(x3 + ((size_t)(m + b + 1)) * D_))[tid];
    v.x -= se.x + gr.x; v.y -= se.y + gr.y; v.z -= se.z + gr.z; v.w -= se.w + gr.w;
  }
  float s = v.x + v.y + v.z + v.w;
  float s2 = v.x * v.x + v.y * v.y + v.z * v.z + v.w * v.w;
#pragma unroll
  for (int off = 32; off; off >>= 1) { s += __shfl_down(s, off); s2 += __shfl_down(s2, off); }
  __shared__ float p1[2], p2[2];
  if ((tid & 63) == 0) { p1[tid >> 6] = s; p2[tid >> 6] = s2; }
  __syncthreads();
  const float S = p1[0] + p1[1], S2 = p2[0] + p2[1];
  const float mu = S * (1.0f / 512.0f);
  const float rs = rsqrtf(fmaxf(S2 * (1.0f / 512.0f) - mu * mu, 0.0f) + 1e-5f);
  const float4 gg = ((const float4*)g)[tid], bb = ((const float4*)be)[tid];
  float4 o;
  o.x = (v.x - mu) * rs * gg.x + bb.x;
  o.y = (v.y - mu) * rs * gg.y + bb.y;
  o.z = (v.z - mu) * rs * gg.z + bb.z;
  o.w = (v.w - mu) * rs * gg.w + bb.w;
  ((float4*)(outF + (size_t)m * D_))[tid] = o;
  if (MODE == 0) {
    bf16* ob = outB + (size_t)m * D_ + tid * 4;
    ob[0] = __float2bfloat16(o.x); ob[1] = __float2bfloat16(o.y);
    ob[2] = __float2bfloat16(o.z); ob[3] = __float2bfloat16(o.w);
  }
}

// ---------------- bf16 MFMA GEMM, swizzled LDS + counted-vmcnt pipeline (T2+T4) ----------------
// One gload_lds16 call stages 64 lanes x 16B = 1024B = 512/BK rows (RPC).
// LDS layout (both-sides swizzle; gload dest linear, global source pre-permuted):
//  BK=64: group = 8 rows x 128B; slot cs of row rr holds global chunk (cs ^ rr)
//  BK=32: group = 16 rows; superrow sr = row pair (128B); slot cs holds idx = cs ^ (sr&7)
// K-loop: stage(next); s_waitcnt vmcnt(TLOADS) [next tile stays in flight];
//         s_barrier; ds_read+MFMA; s_barrier.  vmcnt never drains to 0 mid-loop.
template <int BM, int BN, int BK, int EPI>
__global__ __launch_bounds__(256) void k_gemm(const bf16* __restrict__ A, const bf16* __restrict__ Bw,
                                              const float* __restrict__ bias, float* outF, bf16* __restrict__ outB,
                                              const float* resid, const int M, const int N, const int K,
                                              const int extra) {
  constexpr int WC = (BN >= 128) ? 2 : 1;
  constexpr int WR = 4 / WC;
  constexpr int FM = BM / (WR * 16);
  constexpr int FN = BN / (WC * 16);
  constexpr int RPC = 512 / BK;        // rows staged per gload-call: 1024B / (2*BK B per row)
  constexpr int LA = (BM / RPC) / 4, LB = (BN / RPC) / 4;
  constexpr int KK = BK / 32;
  constexpr int TLOADS = LA + LB;      // per-wave gload_lds ops per tile
  static_assert(LA >= 1 && LB >= 1, "tile too small for staging split");
  __shared__ bf16 lsA[2][BM * BK];
  __shared__ bf16 lsB[2][BN * BK];
  const int tid = threadIdx.x;
  const int w = tid >> 6, lane = tid & 63;
  const int tn = blockIdx.x, tm = blockIdx.y;
  const int wr = w / WC, wc = w % WC;
  const int r16 = lane & 15, hi = lane >> 4;

  // staging lane decode (inverse swizzle on the global source)
  int srowoff, scoloff;
  if constexpr (BK == 64) {
    const int rr = lane >> 3, cs = lane & 7;
    srowoff = rr;                 // 8 rows per call
    scoloff = (cs ^ rr) * 8;
  } else {
    const int sr = lane >> 3, cs = lane & 7;
    const int idx = cs ^ (sr & 7);
    srowoff = sr * 2 + (idx >> 2);  // 16 rows per call
    scoloff = (idx & 3) * 8;
  }

  const f32x4 fzero = {0.f, 0.f, 0.f, 0.f};
  f32x4 acc[FM][FN];
#pragma unroll
  for (int i = 0; i < FM; i++)
#pragma unroll
    for (int jj = 0; jj < FN; jj++) acc[i][jj] = fzero;

  const int NT = K / BK;

  auto stage = [&](int kt, int sel) {
#pragma unroll
    for (int q = 0; q < LA; q++) {
      const int g = w * LA + q;
      int m = tm * BM + g * RPC + srowoff;
      if (m > M - 1) m = M - 1;
      m += (m >> 10) * extra;
      gload_lds16(A + (size_t)m * K + (size_t)kt * BK + scoloff, &lsA[sel][g * 512]);
    }
#pragma unroll
    for (int q = 0; q < LB; q++) {
      const int g = w * LB + q;
      const int n = tn * BN + g * RPC + srowoff;
      gload_lds16(Bw + (size_t)n * K + (size_t)kt * BK + scoloff, &lsB[sel][g * 512]);
    }
  };

  // swizzled fragment read: row = logical row in tile, cc = 16B chunk index within BK row
  auto frag = [&](const bf16* ls, int row, int cc) -> bf16x8 {
    if constexpr (BK == 64) {
      const int g = row >> 3, rr = row & 7;
      return *(const bf16x8*)&ls[g * 512 + rr * 64 + ((cc ^ rr) << 3)];
    } else {
      const int g = row >> 4, rr = row & 15, sr = rr >> 1;
      const int idx = ((rr & 1) << 2) | cc;
      return *(const bf16x8*)&ls[g * 512 + sr * 64 + ((idx ^ (sr & 7)) << 3)];
    }
  };

  stage(0, 0);
  for (int kt = 0; kt < NT; ++kt) {
    const int sel = kt & 1;
    if (kt + 1 < NT) {
      stage(kt + 1, sel ^ 1);   // issue next tile; leave in flight across the barrier
      vm_wait<TLOADS>();        // wait only for buf[sel]'s loads
    } else {
      vm_wait<0>();             // epilogue: drain the last tile
    }
    __builtin_amdgcn_sched_barrier(0);
    __builtin_amdgcn_s_barrier();   // all waves: buf[sel] complete
    __builtin_amdgcn_sched_barrier(0);
#pragma unroll
    for (int kk = 0; kk < KK; ++kk) {
      bf16x8 af[FM], bfv[FN];
#pragma unroll
      for (int i = 0; i < FM; i++)
        af[i] = frag(lsA[sel], wr * (FM * 16) + i * 16 + r16, kk * 4 + hi);
#pragma unroll
      for (int jj = 0; jj < FN; jj++)
        bfv[jj] = frag(lsB[sel], wc * (FN * 16) + jj * 16 + r16, kk * 4 + hi);
#pragma unroll
      for (int i = 0; i < FM; i++)
#pragma unroll
        for (int jj = 0; jj < FN; jj++)
          acc[i][jj] = __builtin_amdgcn_mfma_f32_16x16x32_bf16(af[i], bfv[jj], acc[i][jj], 0, 0, 0);
    }
    if (kt + 1 < NT) {
      __builtin_amdgcn_sched_barrier(0);
      __builtin_amdgcn_s_barrier();  // protect buf[sel] before next iteration overwrites it
      __builtin_amdgcn_sched_barrier(0);
    }
  }

#pragma unroll
  for (int i = 0; i < FM; i++) {
#pragma unroll
    for (int r = 0; r < 4; r++) {
      const int m = tm * BM + wr * (FM * 16) + i * 16 + hi * 4 + r;
      if (m < M) {
#pragma unroll
        for (int jj = 0; jj < FN; jj++) {
          const int n = tn * BN + wc * (FN * 16) + jj * 16 + r16;
          float x = acc[i][jj][r];
          if (bias) x += bias[n];
          const size_t idx = (size_t)m * N + n;
          if (EPI == 0) {
            outF[idx] = x;
          } else if (EPI == 1) {
            outF[idx] = x;
            outB[idx] = __float2bfloat16(x);
          } else if (EPI == 2) {
            outB[idx] = __float2bfloat16(1.0f / (1.0f + __expf(-x)));
          } else {
            outF[idx] = x + resid[idx];
          }
        }
      }
    }
  }
}

// ---------------- workspace layout ----------------
#define MB (size_t)(1u << 20)
static const size_t OFF_A = 0;
static const size_t OFF_C = 32 * MB;
static const size_t OFF_D = 40 * MB;
static const size_t OFF_E = 48 * MB;
static const size_t OFF_F = 54 * MB;
static const size_t OFF_G = 63 * MB;
static const size_t OFF_H = 72 * MB;
static const size_t OFF_J = 88 * MB;
static const size_t OFF_K = 89 * MB;
static const size_t OFF_K2 = 91 * MB;

#define W_IN 0
#define W_OUT 262144
#define W_FF1 524288
#define W_FF2 1572864
#define W_GW 2621440
#define W_SW2 2654208

extern "C" void kernel_launch(void* const* d_in, const int* in_sizes, int n_in, void* d_out, int out_size,
                              void* d_ws, size_t ws_size, hipStream_t stream) {
  (void)in_sizes; (void)n_in; (void)out_size; (void)ws_size;
  const float* res = (const float*)d_in[0];
  const float* level = (const float*)d_in[1];
  const float* gl_z0 = (const float*)d_in[2];
  const float* gl_in_w = (const float*)d_in[3];
  const float* gl_in_b = (const float*)d_in[4];
  const float* gl_sw = (const float*)d_in[5];
  const float* gl_v0 = (const float*)d_in[6];
  const float* gl_out_w = (const float*)d_in[7];
  const float* gl_out_b = (const float*)d_in[8];
  const float* ll_sw = (const float*)d_in[9];
  const float* ll_v0 = (const float*)d_in[10];
  const float* ll_gw = (const float*)d_in[11];
  const float* ll_gb = (const float*)d_in[12];
  const float* ll_sw2 = (const float*)d_in[13];
  const float* ll_sb = (const float*)d_in[14];
  const float* ff_w1 = (const float*)d_in[15];
  const float* ff_w2 = (const float*)d_in[16];
  const float* n1_g = (const float*)d_in[17];
  const float* n1_b = (const float*)d_in[18];
  const float* n2_g = (const float*)d_in[19];
  const float* n2_b = (const float*)d_in[20];

  char* ws = (char*)d_ws;
  float* resT = (float*)(ws + OFF_A);
  float* vbuf = (float*)(ws + OFF_A);
  bf16* hbuf = (bf16*)(ws + OFF_A);
  bf16* res1b = (bf16*)(ws + OFF_C);
  bf16* res2b = (bf16*)(ws + OFF_C);
  bf16* seasb = (bf16*)(ws + OFF_D);
  bf16* wE = (bf16*)(ws + OFF_E);
  bf16* s2b = (bf16*)(ws + OFF_F);
  bf16* grob = (bf16*)(ws + OFF_G);
  float* res2f = (float*)(ws + OFF_H);
  float* comp = (float*)(ws + OFF_J);
  float* gproj = (float*)(ws + OFF_K);
  float* sproj = (float*)(ws + OFF_K2);

  float* o_res = (float*)d_out;
  float* o_level = o_res + 4194304;
  float* o_growth = o_level + 524288;
  float* o_season = o_growth + 4198400;

  k_transpose<<<dim3(16, 32, 8), dim3(32, 8), 0, stream>>>(res, resT);
  k_fft_topk<<<4096, 256, 0, stream>>>(resT, comp);
  k_season<<<dim3(256, 8), 512, 0, stream>>>(comp, res, o_season, res1b, seasb);
  k_cvt_all<<<(CVT_TOTAL / 4 + 255) / 256, 256, 0, stream>>>(gl_in_w, gl_out_w, ff_w1, ff_w2, ll_gw, ll_sw2, wE);
  // v = res1 @ gl_in_w^T + b       (64x128 tile, BK=64, TLOADS=6)
  k_gemm<64, 128, 64, 0><<<dim3(4, 128), 256, 0, stream>>>(res1b, wE + W_IN, gl_in_b, vbuf, nullptr, nullptr, 8192, 512, 512, 0);
  k_growth_scan2<<<64, 1024, 0, stream>>>(vbuf, gl_z0, gl_sw, gl_v0, s2b);
  // growth = s2 @ gl_out_w^T + b   (M=8200 -> 129 row tiles)
  k_gemm<64, 128, 64, 1><<<dim3(4, 129), 256, 0, stream>>>(s2b, wE + W_OUT, gl_out_b, o_growth, grob, nullptr, 8200, 512, 512, 0);
  k_ln<0><<<8192, 128, 0, stream>>>(res, o_season, o_growth, n1_g, n1_b, res2f, res2b);
  // FF1: 128x128 BK=32, TLOADS=4
  k_gemm<128, 128, 32, 2><<<dim3(16, 64), 256, 0, stream>>>(res2b, wE + W_FF1, nullptr, nullptr, hbuf, nullptr, 8192, 2048, 512, 0);
  // FF2: 64x128 BK=64, K=2048
  k_gemm<64, 128, 64, 3><<<dim3(4, 128), 256, 0, stream>>>(hbuf, wE + W_FF2, nullptr, res2f, nullptr, res2f, 8192, 512, 2048, 0);
  k_ln<1><<<8192, 128, 0, stream>>>(res2f, nullptr, nullptr, n2_g, n2_b, o_res, nullptr);
  // gproj/sproj: 64x64 BK=64
  k_gemm<64, 64, 64, 0><<<dim3(1, 128), 256, 0, stream>>>(grob, wE + W_GW, ll_gb, gproj, nullptr, nullptr, 8192, 64, 512, 1);
  k_gemm<64, 64, 64, 0><<<dim3(1, 128), 256, 0, stream>>>(seasb, wE + W_SW2, ll_sb, sproj, nullptr, nullptr, 8192, 64, 512, 0);
  k_level_scan2<<<8, 1024, 0, stream>>>(level, gproj, sproj, ll_sw, ll_v0, o_level);
}